// Round 7
// baseline (186.448 us; speedup 1.0000x reference)
//
#include <hip/hip_runtime.h>
#include <math.h>

#define BB 4
#define TT 2048
#define EE 384
#define HH 6
#define DD 64
#define MM (BB*TT)   // 8192 tokens

typedef __attribute__((ext_vector_type(8))) short bf16x8;
typedef __attribute__((ext_vector_type(4))) float f32x4;

__device__ __forceinline__ unsigned short f2bf(float f) {
    unsigned int u = __float_as_uint(f);
    u = (u + 0x7FFFu + ((u >> 16) & 1u)) >> 16;   // RNE
    return (unsigned short)u;
}
__device__ __forceinline__ float bf2f(unsigned short u) {
    return __uint_as_float(((unsigned int)u) << 16);
}
__device__ __forceinline__ unsigned int pk2(float a, float b) {
    return (unsigned int)f2bf(a) | ((unsigned int)f2bf(b) << 16);
}
// HW packed fp32->bf16 (RNE) -- 1 VALU op for 2 values (no builtin; inline asm)
__device__ __forceinline__ unsigned int cvtpk(float lo, float hi) {
    unsigned int r;
    asm("v_cvt_pk_bf16_f32 %0, %1, %2" : "=v"(r) : "v"(lo), "v"(hi));
    return r;
}

// ------------- fp32 -> bf16 conversion: WEIGHTS ONLY (4 x 144 blocks) ----------------
__global__ __launch_bounds__(256) void k_cvt(const float* __restrict__ wq,
                                             const float* __restrict__ wo,
                                             const float* __restrict__ w1,
                                             const float* __restrict__ w2,
                                             unsigned short* __restrict__ wqb,
                                             unsigned short* __restrict__ wob,
                                             unsigned short* __restrict__ w1b,
                                             unsigned short* __restrict__ w2b)
{
    int wi = blockIdx.x / 144, off = (blockIdx.x % 144) * 256;
    const float* s4[4] = {wq, wo, w1, w2};
    unsigned short* d4[4] = {wqb, wob, w1b, w2b};
    const float* src = s4[wi]; unsigned short* dst = d4[wi];
    int i = off + threadIdx.x;
    float4 v = ((const float4*)src)[i];
    uint2 o; o.x = pk2(v.x, v.y); o.y = pk2(v.z, v.w);
    ((uint2*)dst)[i] = o;
}

// ------------- q-GEMM (R23: distance-2 weight prefetch; neutral but harmless) --------
__global__ __launch_bounds__(256, 2) void k_qgemm(const float* __restrict__ x,
                                                  const unsigned short* __restrict__ W,
                                                  unsigned short* __restrict__ qbf,
                                                  unsigned short* __restrict__ qbfT)
{
    __shared__ unsigned short Xs[32][396];
    __shared__ unsigned short Ts[32][200];
    const int tid = threadIdx.x;
    const int w = tid >> 6, lane = tid & 63;
    const int fr = lane & 15, quad = lane >> 4;
    const int m0 = blockIdx.x * 32;
    const int n0 = blockIdx.y * 192 + w * 48;
    const unsigned short* Wp = W + (size_t)(n0 + fr) * EE + quad * 8;

    // ---- stage + convert A tile (32 x 384) ----
    {
        const float* xp = x + (size_t)m0 * EE;
        #pragma unroll
        for (int it = 0; it < 12; it++) {
            int idx = it * 1024 + tid * 4;
            int row = idx / EE, col = idx % EE;
            float4 v = *(const float4*)(xp + idx);
            uint2 o; o.x = pk2(v.x, v.y); o.y = pk2(v.z, v.w);
            *(uint2*)&Xs[row][col] = o;
        }
    }

    f32x4 acc[2][3];
    bf16x8 bC[3], bN[3], bT[3];
    #pragma unroll
    for (int mt = 0; mt < 2; mt++)
        #pragma unroll
        for (int nt = 0; nt < 3; nt++) acc[mt][nt] = (f32x4){0.f, 0.f, 0.f, 0.f};
    #pragma unroll
    for (int nt = 0; nt < 3; nt++) bC[nt] = *(const bf16x8*)(Wp + (size_t)nt * 16 * EE);
    #pragma unroll
    for (int nt = 0; nt < 3; nt++) bN[nt] = *(const bf16x8*)(Wp + (size_t)nt * 16 * EE + 32);
    #pragma unroll
    for (int nt = 0; nt < 3; nt++) bT[nt] = bN[nt];
    __syncthreads();   // Xs visible

    #pragma unroll
    for (int k0 = 0; k0 < 12; k0++) {
        if (k0 < 10) {
            #pragma unroll
            for (int nt = 0; nt < 3; nt++)
                bT[nt] = *(const bf16x8*)(Wp + (size_t)nt * 16 * EE + (k0 + 2) * 32);
        }
        bf16x8 a0 = *(const bf16x8*)&Xs[fr][k0 * 32 + quad * 8];
        bf16x8 a1 = *(const bf16x8*)&Xs[16 + fr][k0 * 32 + quad * 8];
        #pragma unroll
        for (int nt = 0; nt < 3; nt++) {
            acc[0][nt] = __builtin_amdgcn_mfma_f32_16x16x32_bf16(a0, bC[nt], acc[0][nt], 0, 0, 0);
            acc[1][nt] = __builtin_amdgcn_mfma_f32_16x16x32_bf16(a1, bC[nt], acc[1][nt], 0, 0, 0);
        }
        #pragma unroll
        for (int nt = 0; nt < 3; nt++) { bC[nt] = bN[nt]; bN[nt] = bT[nt]; }
    }

    // epilogue: direct qbf writes + LDS stage for transposed qbfT
    const int bglob = m0 >> 11, t0 = m0 & 2047;
    #pragma unroll
    for (int nt = 0; nt < 3; nt++) {
        int nl = w * 48 + nt * 16 + fr;
        int n = blockIdx.y * 192 + nl;
        int h = n >> 6, d = n & 63;
        #pragma unroll
        for (int mt = 0; mt < 2; mt++)
            #pragma unroll
            for (int r = 0; r < 4; r++) {
                int ml = mt * 16 + quad * 4 + r;
                unsigned short bf = f2bf(acc[mt][nt][r]);
                qbf[((size_t)(bglob * HH + h) * TT + t0 + ml) * DD + d] = bf;
                Ts[ml][nl] = bf;
            }
    }
    __syncthreads();
    if (tid < 192) {
        int nl = tid;
        int n = blockIdx.y * 192 + nl;
        int h = n >> 6, d = n & 63;
        unsigned short tmp[32];
        #pragma unroll
        for (int i = 0; i < 32; i++) tmp[i] = Ts[i][nl];
        unsigned short* dst = qbfT + ((size_t)(bglob * HH + h) * DD + d) * TT + t0;
        *(uint4*)(dst)      = *(const uint4*)&tmp[0];
        *(uint4*)(dst + 8)  = *(const uint4*)&tmp[8];
        *(uint4*)(dst + 16) = *(const uint4*)&tmp[16];
        *(uint4*)(dst + 24) = *(const uint4*)&tmp[24];
    }
}

// ------------- MFMA flash attention (R25: pair-block + single-buffer, 4 blocks/CU) --
// R24 concurrent tile-pair structure kept (waves 0-3: tile p, 4-7: tile 63-p, shared
// K/V stream). Changes: K/V SINGLE-buffered (18.4KB) -> LDS 27.9KB, and
// __launch_bounds__(512,8) squeezes VGPR 68->64. Both limits then admit 4 blocks/CU
// = 32 waves/CU (HW max, was 24). Cost: +1 barrier/iter (reads-done before overwrite)
// -- backfilled by 3 other co-resident blocks. Numerics bit-identical.
__global__ __launch_bounds__(512, 8) void k_attn(const unsigned short* __restrict__ qbf,
                                                 const unsigned short* __restrict__ qbfT,
                                                 unsigned short* __restrict__ cat)
{
    __shared__ unsigned short KV[2][64][72];   // [0]=K tile, [1]=V tile (single buffer)
    __shared__ unsigned short Ps[64][72];
    __shared__ float lsc[64];
    float (*Oc)[68] = (float(*)[68])&KV[0][0][0];   // overlay 64x68x4=17408 <= 18432

    const int id = blockIdx.x;              // 0..767
    const int xcd = id & 7, j = id >> 3;
    const int bh = xcd * 3 + (j % 3);       // XCD-affine: 3 heads per XCD
    const int p = j / 3;                    // 0..31 ascending => longest blocks first
    const int bb = bh / HH, hh = bh % HH;
    const int tid = threadIdx.x;
    const int w = tid >> 6, lane = tid & 63;
    const int tg = w >> 2, wv = w & 3;      // tile group (0: tile p, 1: tile 63-p)
    const int qhalf = wv & 1, keyhalf = wv >> 1;
    const int fr = lane & 15, quad = lane >> 4;
    const int fc = quad * 8;
    const unsigned short* qb  = qbf  + (size_t)bh * TT * DD;
    const unsigned short* qtb = qbfT + (size_t)bh * DD * TT;
    const int lr = tid >> 3, lc = (tid & 7) * 8;   // 512-thr staging: 1 uint4 K + 1 V
    const float EXSC = 0.18033688011112042f;       // 0.125 * log2(e)

    const int tile = tg ? (63 - p) : p;
    const int m0 = tile * 32;
    const int nkt = (tile >> 1) + 1;        // this tile group's iteration count
    const int nktB = ((63 - p) >> 1) + 1;   // block-wide iteration count (max of pair)

    // ---- prologue: stage K/V tile 0 + load Q frags (direct, coalesced) ----
    {
        uint4 kr0 = *(const uint4*)(qb + (size_t)lr * DD + lc);
        uint4 vr0 = *(const uint4*)(qtb + (size_t)lr * TT + lc);
        *(uint4*)&KV[0][lr][lc] = kr0;
        *(uint4*)&KV[1][lr][lc] = vr0;
    }
    const unsigned short* qp = qb + (size_t)(m0 + qhalf * 16 + fr) * DD + fc;
    const bf16x8 qA0 = *(const bf16x8*)(qp);
    const bf16x8 qA1 = *(const bf16x8*)(qp + 32);
    __syncthreads();   // tile 0 visible

    f32x4 accO[4];
    #pragma unroll
    for (int dt = 0; dt < 4; dt++) accO[dt] = (f32x4){0.f, 0.f, 0.f, 0.f};
    float ls[4] = {0.f, 0.f, 0.f, 0.f};
    const int rowbase = m0 + qhalf * 16 + quad * 4;
    const int prow = tg * 32 + qhalf * 16 + quad * 4;   // row in shared Ps/Oc/lsc space

    uint4 kr, vr;
    for (int kt = 0; kt < nktB; kt++) {
        const int s0 = kt * 64;
        if (kt < nktB - 1) {   // prefetch next K/V tile into regs (full-compute cover)
            kr = *(const uint4*)(qb + (size_t)(s0 + 64 + lr) * DD + lc);
            vr = *(const uint4*)(qtb + (size_t)lr * TT + s0 + 64 + lc);
        }

        if (kt < nkt) {        // tile-p waves park here once past their diagonal
            f32x4 S[2];
            #pragma unroll
            for (int nt = 0; nt < 2; nt++) {
                f32x4 acc = (f32x4){0.f, 0.f, 0.f, 0.f};
                bf16x8 b0 = *(const bf16x8*)&KV[0][keyhalf * 32 + nt * 16 + fr][fc];
                acc = __builtin_amdgcn_mfma_f32_16x16x32_bf16(qA0, b0, acc, 0, 0, 0);
                bf16x8 b1 = *(const bf16x8*)&KV[0][keyhalf * 32 + nt * 16 + fr][fc + 32];
                acc = __builtin_amdgcn_mfma_f32_16x16x32_bf16(qA1, b1, acc, 0, 0, 0);
                S[nt] = acc;
            }

            const bool edge = (kt == nkt - 1);
            #pragma unroll
            for (int nt = 0; nt < 2; nt++) {
                const int col = keyhalf * 32 + nt * 16 + fr;
                float pv[4];
                if (edge) {
                    const int jg = s0 + col;
                    #pragma unroll
                    for (int r = 0; r < 4; r++) {
                        float s = S[nt][r];
                        pv[r] = (jg <= rowbase + r && s != 0.0f)
                                ? __builtin_amdgcn_exp2f(s * EXSC) : 0.0f;
                        ls[r] += pv[r];
                    }
                } else {       // fully below diagonal: no causal compare needed
                    #pragma unroll
                    for (int r = 0; r < 4; r++) {
                        float s = S[nt][r];
                        pv[r] = (s != 0.0f) ? __builtin_amdgcn_exp2f(s * EXSC) : 0.0f;
                        ls[r] += pv[r];
                    }
                }
                unsigned int pk0 = cvtpk(pv[0], pv[1]);
                unsigned int pk1 = cvtpk(pv[2], pv[3]);
                Ps[prow + 0][col] = (unsigned short)(pk0);
                Ps[prow + 1][col] = (unsigned short)(pk0 >> 16);
                Ps[prow + 2][col] = (unsigned short)(pk1);
                Ps[prow + 3][col] = (unsigned short)(pk1 >> 16);
            }

            // P exchange is intra-wave (own tg/qhalf/keyhalf quadrant): no barrier
            bf16x8 pA = *(const bf16x8*)&Ps[tg * 32 + qhalf * 16 + fr][keyhalf * 32 + fc];
            #pragma unroll
            for (int dt = 0; dt < 4; dt++) {
                bf16x8 v0 = *(const bf16x8*)&KV[1][dt * 16 + fr][keyhalf * 32 + fc];
                accO[dt] = __builtin_amdgcn_mfma_f32_16x16x32_bf16(pA, v0, accO[dt], 0, 0, 0);
            }
        }

        if (kt < nktB - 1) {
            __syncthreads();   // all K/V reads of tile kt complete (single buffer)
            *(uint4*)&KV[0][lr][lc] = kr;
            *(uint4*)&KV[1][lr][lc] = vr;
            __syncthreads();   // tile kt+1 visible
        }
    }

    __syncthreads();   // final-iter LDS reads complete before Oc-overlay write
    #pragma unroll
    for (int r = 0; r < 4; r++) {
        #pragma unroll
        for (int o = 1; o < 16; o <<= 1) ls[r] += __shfl_xor(ls[r], o, 64);
    }
    if (keyhalf == 1) {
        #pragma unroll
        for (int dt = 0; dt < 4; dt++)
            #pragma unroll
            for (int r = 0; r < 4; r++)
                Oc[prow + r][dt * 16 + fr] = accO[dt][r];
        if (fr == 0) {
            #pragma unroll
            for (int r = 0; r < 4; r++) lsc[prow + r] = ls[r];
        }
    }
    __syncthreads();
    if (keyhalf == 0) {
        float il[4];
        #pragma unroll
        for (int r = 0; r < 4; r++) il[r] = 1.0f / (ls[r] + lsc[prow + r]);
        #pragma unroll
        for (int dt = 0; dt < 4; dt++) {
            #pragma unroll
            for (int r = 0; r < 4; r++) {
                float o = accO[dt][r] + Oc[prow + r][dt * 16 + fr];
                int t = rowbase + r;
                cat[((size_t)bb * TT + t) * EE + hh * DD + dt * 16 + fr] =
                    f2bf(o * il[r]);
            }
        }
    }
}

// ------------- fused proj+LN1 + FFN1 + FFN2+LN2 (R23, unchanged) --------------------
__global__ __launch_bounds__(512, 2) void k_ffn(const unsigned short* __restrict__ catb,
                                                const unsigned short* __restrict__ wob,
                                                const float* __restrict__ bo,
                                                const float* __restrict__ x,
                                                const float* __restrict__ g1,
                                                const float* __restrict__ be1,
                                                const unsigned short* __restrict__ w1b,
                                                const float* __restrict__ b1,
                                                const unsigned short* __restrict__ w2b,
                                                const float* __restrict__ b2,
                                                const float* __restrict__ g2,
                                                const float* __restrict__ be2,
                                                float* __restrict__ out)
{
    __shared__ unsigned short X1s[32][392];
    __shared__ unsigned short H1s[32][392];
    __shared__ float ssum[32][8];
    __shared__ float ssq[32][8];
    const int tid = threadIdx.x;
    const int w = tid >> 6, lane = tid & 63;
    const int fr = lane & 15, quad = lane >> 4;
    const int m0 = blockIdx.x * 32;
    const int n0 = w * 48;

    f32x4 acc[2][3];
    bf16x8 bC[3], bN[3], bT[3];
    const unsigned short* Wp1 = w1b + (size_t)(n0 + fr) * EE + quad * 8;
    const unsigned short* Wp2 = w2b + (size_t)(n0 + fr) * EE + quad * 8;

    // ================= GEMM1: proj = catb @ Wo^T (2 m-tiles) =================
    {
        const unsigned short* Ap0 = catb + (size_t)(m0 + fr) * EE + quad * 8;
        const unsigned short* Ap1 = Ap0 + 16 * EE;
        const unsigned short* Wp = wob + (size_t)(n0 + fr) * EE + quad * 8;
        #pragma unroll
        for (int mt = 0; mt < 2; mt++)
            #pragma unroll
            for (int nt = 0; nt < 3; nt++) acc[mt][nt] = (f32x4){0.f, 0.f, 0.f, 0.f};
        #pragma unroll
        for (int nt = 0; nt < 3; nt++) bC[nt] = *(const bf16x8*)(Wp + (size_t)nt * 16 * EE);
        #pragma unroll
        for (int nt = 0; nt < 3; nt++) bN[nt] = *(const bf16x8*)(Wp + (size_t)nt * 16 * EE + 32);
        #pragma unroll
        for (int nt = 0; nt < 3; nt++) bT[nt] = bN[nt];
        bf16x8 aC0 = *(const bf16x8*)(Ap0);
        bf16x8 aC1 = *(const bf16x8*)(Ap1);
        bf16x8 aN0 = *(const bf16x8*)(Ap0 + 32);
        bf16x8 aN1 = *(const bf16x8*)(Ap1 + 32);
        bf16x8 aT0 = aN0, aT1 = aN1;
        #pragma unroll
        for (int k0 = 0; k0 < 12; k0++) {
            if (k0 < 10) {
                #pragma unroll
                for (int nt = 0; nt < 3; nt++)
                    bT[nt] = *(const bf16x8*)(Wp + (size_t)nt * 16 * EE + (k0 + 2) * 32);
                aT0 = *(const bf16x8*)(Ap0 + (k0 + 2) * 32);
                aT1 = *(const bf16x8*)(Ap1 + (k0 + 2) * 32);
            }
            #pragma unroll
            for (int nt = 0; nt < 3; nt++) {
                acc[0][nt] = __builtin_amdgcn_mfma_f32_16x16x32_bf16(aC0, bC[nt], acc[0][nt], 0, 0, 0);
                acc[1][nt] = __builtin_amdgcn_mfma_f32_16x16x32_bf16(aC1, bC[nt], acc[1][nt], 0, 0, 0);
            }
            aC0 = aN0; aC1 = aN1; aN0 = aT0; aN1 = aT1;
            #pragma unroll
            for (int nt = 0; nt < 3; nt++) { bC[nt] = bN[nt]; bN[nt] = bT[nt]; }
        }
    }
    // early prefetch of GEMM2's first two weight stages (overlaps LN1 VALU)
    #pragma unroll
    for (int nt = 0; nt < 3; nt++) bC[nt] = *(const bf16x8*)(Wp1 + (size_t)nt * 16 * EE);
    #pragma unroll
    for (int nt = 0; nt < 3; nt++) bN[nt] = *(const bf16x8*)(Wp1 + (size_t)nt * 16 * EE + 32);
    // + bo + resid(x) -> LN1 stats
    {
        float s1[2][4] = {{0.f,0.f,0.f,0.f},{0.f,0.f,0.f,0.f}};
        float s2[2][4] = {{0.f,0.f,0.f,0.f},{0.f,0.f,0.f,0.f}};
        #pragma unroll
        for (int nt = 0; nt < 3; nt++) {
            int n = n0 + nt * 16 + fr;
            float bv = bo[n];
            #pragma unroll
            for (int mt = 0; mt < 2; mt++)
                #pragma unroll
                for (int r = 0; r < 4; r++) {
                    float v = acc[mt][nt][r] + bv
                            + x[(size_t)(m0 + mt * 16 + quad * 4 + r) * EE + n];
                    acc[mt][nt][r] = v;
                    s1[mt][r] += v;
                    s2[mt][r] += v * v;
                }
        }
        #pragma unroll
        for (int mt = 0; mt < 2; mt++)
            #pragma unroll
            for (int r = 0; r < 4; r++) {
                #pragma unroll
                for (int o = 1; o < 16; o <<= 1) {
                    s1[mt][r] += __shfl_xor(s1[mt][r], o, 64);
                    s2[mt][r] += __shfl_xor(s2[mt][r], o, 64);
                }
            }
        if (fr == 0) {
            #pragma unroll
            for (int mt = 0; mt < 2; mt++)
                #pragma unroll
                for (int r = 0; r < 4; r++) {
                    ssum[mt * 16 + quad * 4 + r][w] = s1[mt][r];
                    ssq [mt * 16 + quad * 4 + r][w] = s2[mt][r];
                }
        }
    }
    __syncthreads();
    {
        #pragma unroll
        for (int mt = 0; mt < 2; mt++) {
            float mu[4], rs[4];
            #pragma unroll
            for (int r = 0; r < 4; r++) {
                int row = mt * 16 + quad * 4 + r;
                float t1 = 0.f, t2 = 0.f;
                #pragma unroll
                for (int q = 0; q < 8; q++) { t1 += ssum[row][q]; t2 += ssq[row][q]; }
                mu[r] = t1 * (1.0f / EE);
                float var = t2 * (1.0f / EE) - mu[r] * mu[r];
                rs[r] = rsqrtf(var + 1e-5f);
            }
            #pragma unroll
            for (int nt = 0; nt < 3; nt++) {
                int n = n0 + nt * 16 + fr;
                float gv = g1[n], bev = be1[n];
                #pragma unroll
                for (int r = 0; r < 4; r++) {
                    float v = (acc[mt][nt][r] - mu[r]) * rs[r] * gv + bev;
                    X1s[mt * 16 + quad * 4 + r][n] = f2bf(v);
                }
            }
        }
    }
    __syncthreads();

    // ================= GEMM2: h1 = relu(x1 @ W1^T + b1) =================
    {
        #pragma unroll
        for (int mt = 0; mt < 2; mt++)
            #pragma unroll
            for (int nt = 0; nt < 3; nt++) acc[mt][nt] = (f32x4){0.f, 0.f, 0.f, 0.f};
        #pragma unroll
        for (int nt = 0; nt < 3; nt++) bT[nt] = bN[nt];
        #pragma unroll
        for (int k0 = 0; k0 < 12; k0++) {
            if (k0 < 10) {
                #pragma unroll
                for (int nt = 0; nt < 3; nt++)
                    bT[nt] = *(const bf16x8*)(Wp1 + (size_t)nt * 16 * EE + (k0 + 2) * 32);
            }
            bf16x8 a0 = *(const bf16x8*)&X1s[fr][k0 * 32 + quad * 8];
            bf16x8 a1 = *(const bf16x8*)&X1s[16 + fr][k0 * 32 + quad * 8];
            #pragma unroll
            for (int nt = 0; nt < 3; nt++) {
                acc[0][nt] = __builtin_amdgcn_mfma_f32_16x16x32_bf16(a0, bC[nt], acc[0][nt], 0, 0, 0);
                acc[1][nt] = __builtin_amdgcn_mfma_f32_16x16x32_bf16(a1, bC[nt], acc[1][nt], 0, 0, 0);
            }
            #pragma unroll
            for (int nt = 0; nt < 3; nt++) { bC[nt] = bN[nt]; bN[nt] = bT[nt]; }
        }
        // early prefetch of GEMM3's first two weight stages (overlaps relu/store VALU)
        #pragma unroll
        for (int nt = 0; nt < 3; nt++) bC[nt] = *(const bf16x8*)(Wp2 + (size_t)nt * 16 * EE);
        #pragma unroll
        for (int nt = 0; nt < 3; nt++) bN[nt] = *(const bf16x8*)(Wp2 + (size_t)nt * 16 * EE + 32);
        #pragma unroll
        for (int nt = 0; nt < 3; nt++) {
            int n = n0 + nt * 16 + fr;
            float bv = b1[n];
            #pragma unroll
            for (int mt = 0; mt < 2; mt++)
                #pragma unroll
                for (int r = 0; r < 4; r++)
                    H1s[mt * 16 + quad * 4 + r][n] = f2bf(fmaxf(acc[mt][nt][r] + bv, 0.0f));
        }
    }
    __syncthreads();

    // ================= GEMM3: ff = h1 @ W2^T + b2; LN2(x1 + ff) -> out =================
    {
        #pragma unroll
        for (int mt = 0; mt < 2; mt++)
            #pragma unroll
            for (int nt = 0; nt < 3; nt++) acc[mt][nt] = (f32x4){0.f, 0.f, 0.f, 0.f};
        #pragma unroll
        for (int nt = 0; nt < 3; nt++) bT[nt] = bN[nt];
        #pragma unroll
        for (int k0 = 0; k0 < 12; k0++) {
            if (k0 < 10) {
                #pragma unroll
                for (int nt = 0; nt < 3; nt++)
                    bT[nt] = *(const bf16x8*)(Wp2 + (size_t)nt * 16 * EE + (k0 + 2) * 32);
            }
            bf16x8 a0 = *(const bf16x8*)&H1s[fr][k0 * 32 + quad * 8];
            bf16x8 a1 = *(const bf16x8*)&H1s[16 + fr][k0 * 32 + quad * 8];
            #pragma unroll
            for (int nt = 0; nt < 3; nt++) {
                acc[0][nt] = __builtin_amdgcn_mfma_f32_16x16x32_bf16(a0, bC[nt], acc[0][nt], 0, 0, 0);
                acc[1][nt] = __builtin_amdgcn_mfma_f32_16x16x32_bf16(a1, bC[nt], acc[1][nt], 0, 0, 0);
            }
            #pragma unroll
            for (int nt = 0; nt < 3; nt++) { bC[nt] = bN[nt]; bN[nt] = bT[nt]; }
        }
    }
    {
        float s1[2][4] = {{0.f,0.f,0.f,0.f},{0.f,0.f,0.f,0.f}};
        float s2[2][4] = {{0.f,0.f,0.f,0.f},{0.f,0.f,0.f,0.f}};
        #pragma unroll
        for (int nt = 0; nt < 3; nt++) {
            int n = n0 + nt * 16 + fr;
            float bv = b2[n];
            #pragma unroll
            for (int mt = 0; mt < 2; mt++)
                #pragma unroll
                for (int r = 0; r < 4; r++) {
                    float v = acc[mt][nt][r] + bv + bf2f(X1s[mt * 16 + quad * 4 + r][n]);
                    acc[mt][nt][r] = v;
                    s1[mt][r] += v;
                    s2[mt][r] += v * v;
                }
        }
        #pragma unroll
        for (int mt = 0; mt < 2; mt++)
            #pragma unroll
            for (int r = 0; r < 4; r++) {
                #pragma unroll
                for (int o = 1; o < 16; o <<= 1) {
                    s1[mt][r] += __shfl_xor(s1[mt][r], o, 64);
                    s2[mt][r] += __shfl_xor(s2[mt][r], o, 64);
                }
            }
        if (fr == 0) {
            #pragma unroll
            for (int mt = 0; mt < 2; mt++)
                #pragma unroll
                for (int r = 0; r < 4; r++) {
                    ssum[mt * 16 + quad * 4 + r][w] = s1[mt][r];
                    ssq [mt * 16 + quad * 4 + r][w] = s2[mt][r];
                }
        }
    }
    __syncthreads();
    {
        #pragma unroll
        for (int mt = 0; mt < 2; mt++) {
            float mu[4], rs[4];
            #pragma unroll
            for (int r = 0; r < 4; r++) {
                int row = mt * 16 + quad * 4 + r;
                float u1 = 0.f, u2 = 0.f;
                #pragma unroll
                for (int q = 0; q < 8; q++) { u1 += ssum[row][q]; u2 += ssq[row][q]; }
                mu[r] = u1 * (1.0f / EE);
                float var = u2 * (1.0f / EE) - mu[r] * mu[r];
                rs[r] = rsqrtf(var + 1e-5f);
            }
            #pragma unroll
            for (int nt = 0; nt < 3; nt++) {
                int n = n0 + nt * 16 + fr;
                float gv = g2[n], bev = be2[n];
                #pragma unroll
                for (int r = 0; r < 4; r++)
                    out[(size_t)(m0 + mt * 16 + quad * 4 + r) * EE + n] =
                        (acc[mt][nt][r] - mu[r]) * rs[r] * gv + bev;
            }
        }
    }
}

extern "C" void kernel_launch(void* const* d_in, const int* in_sizes, int n_in,
                              void* d_out, int out_size, void* d_ws, size_t ws_size,
                              hipStream_t stream) {
    (void)in_sizes; (void)n_in; (void)out_size; (void)ws_size;
    const float* x   = (const float*)d_in[0];
    const float* Wq  = (const float*)d_in[1];
    const float* Wo  = (const float*)d_in[2];
    const float* bo  = (const float*)d_in[3];
    const float* W1  = (const float*)d_in[4];
    const float* b1  = (const float*)d_in[5];
    const float* W2  = (const float*)d_in[6];
    const float* b2  = (const float*)d_in[7];
    const float* g1  = (const float*)d_in[8];
    const float* be1 = (const float*)d_in[9];
    const float* g2  = (const float*)d_in[10];
    const float* be2 = (const float*)d_in[11];
    float* out = (float*)d_out;

    float* ws = (float*)d_ws;
    const size_t SZ = (size_t)MM * EE;    // 3,145,728 elems / region (12.6 MB fp32)
    float* S1 = ws + SZ;                   // qbf + qbfT (bf16, fills region exactly)
    float* S2 = ws + 2 * SZ;               // catb (bf16)
    float* S3 = ws + 3 * SZ;               // weight bf16 copies

    unsigned short* qbf  = (unsigned short*)S1;
    unsigned short* qbfT = qbf + (size_t)BB * HH * TT * DD;   // AFTER all of qbf!
    unsigned short* catb = (unsigned short*)S2;
    unsigned short* wqb  = (unsigned short*)S3;
    unsigned short* wob  = wqb + (size_t)EE * EE;
    unsigned short* w1b  = wob + (size_t)EE * EE;
    unsigned short* w2b  = w1b + (size_t)EE * EE;

    k_cvt<<<dim3(4 * 144), dim3(256), 0, stream>>>(Wq, Wo, W1, W2, wqb, wob, w1b, w2b);
    k_qgemm<<<dim3(MM / 32, 2), dim3(256), 0, stream>>>(x, wqb, qbf, qbfT);
    k_attn<<<dim3(768), dim3(512), 0, stream>>>(qbf, qbfT, catb);
    k_ffn<<<dim3(MM / 32), dim3(512), 0, stream>>>(catb, wob, bo, x, g1, be1,
                                                   w1b, b1, w2b, b2, g2, be2, out);
}

// Round 8
// 170.027 us; speedup vs baseline: 1.0966x; 1.0966x over previous
//
#include <hip/hip_runtime.h>
#include <math.h>

#define BB 4
#define TT 2048
#define EE 384
#define HH 6
#define DD 64
#define MM (BB*TT)   // 8192 tokens

typedef __attribute__((ext_vector_type(8))) short bf16x8;
typedef __attribute__((ext_vector_type(4))) float f32x4;

__device__ __forceinline__ unsigned short f2bf(float f) {
    unsigned int u = __float_as_uint(f);
    u = (u + 0x7FFFu + ((u >> 16) & 1u)) >> 16;   // RNE
    return (unsigned short)u;
}
__device__ __forceinline__ float bf2f(unsigned short u) {
    return __uint_as_float(((unsigned int)u) << 16);
}
__device__ __forceinline__ unsigned int pk2(float a, float b) {
    return (unsigned int)f2bf(a) | ((unsigned int)f2bf(b) << 16);
}
// HW packed fp32->bf16 (RNE) -- 1 VALU op for 2 values (no builtin; inline asm)
__device__ __forceinline__ unsigned int cvtpk(float lo, float hi) {
    unsigned int r;
    asm("v_cvt_pk_bf16_f32 %0, %1, %2" : "=v"(r) : "v"(lo), "v"(hi));
    return r;
}

// ------------- fp32 -> bf16 conversion: WEIGHTS ONLY (4 x 144 blocks) ----------------
__global__ __launch_bounds__(256) void k_cvt(const float* __restrict__ wq,
                                             const float* __restrict__ wo,
                                             const float* __restrict__ w1,
                                             const float* __restrict__ w2,
                                             unsigned short* __restrict__ wqb,
                                             unsigned short* __restrict__ wob,
                                             unsigned short* __restrict__ w1b,
                                             unsigned short* __restrict__ w2b)
{
    int wi = blockIdx.x / 144, off = (blockIdx.x % 144) * 256;
    const float* s4[4] = {wq, wo, w1, w2};
    unsigned short* d4[4] = {wqb, wob, w1b, w2b};
    const float* src = s4[wi]; unsigned short* dst = d4[wi];
    int i = off + threadIdx.x;
    float4 v = ((const float4*)src)[i];
    uint2 o; o.x = pk2(v.x, v.y); o.y = pk2(v.z, v.w);
    ((uint2*)dst)[i] = o;
}

// ------------- q-GEMM (R26: occupancy 2->4 blocks/CU) --------------------------------
// Latency-bound at 4 waves/SIMD; LDS 38KB x 4 = 152KB fits. launch_bounds(256,4)
// caps VGPR at 128 (live usage ~100 -- no spill headroom issue, unlike R25's 64-cap).
__global__ __launch_bounds__(256, 4) void k_qgemm(const float* __restrict__ x,
                                                  const unsigned short* __restrict__ W,
                                                  unsigned short* __restrict__ qbf,
                                                  unsigned short* __restrict__ qbfT)
{
    __shared__ unsigned short Xs[32][396];
    __shared__ unsigned short Ts[32][200];
    const int tid = threadIdx.x;
    const int w = tid >> 6, lane = tid & 63;
    const int fr = lane & 15, quad = lane >> 4;
    const int m0 = blockIdx.x * 32;
    const int n0 = blockIdx.y * 192 + w * 48;
    const unsigned short* Wp = W + (size_t)(n0 + fr) * EE + quad * 8;

    // ---- stage + convert A tile (32 x 384) ----
    {
        const float* xp = x + (size_t)m0 * EE;
        #pragma unroll
        for (int it = 0; it < 12; it++) {
            int idx = it * 1024 + tid * 4;
            int row = idx / EE, col = idx % EE;
            float4 v = *(const float4*)(xp + idx);
            uint2 o; o.x = pk2(v.x, v.y); o.y = pk2(v.z, v.w);
            *(uint2*)&Xs[row][col] = o;
        }
    }

    f32x4 acc[2][3];
    bf16x8 bC[3], bN[3], bT[3];
    #pragma unroll
    for (int mt = 0; mt < 2; mt++)
        #pragma unroll
        for (int nt = 0; nt < 3; nt++) acc[mt][nt] = (f32x4){0.f, 0.f, 0.f, 0.f};
    #pragma unroll
    for (int nt = 0; nt < 3; nt++) bC[nt] = *(const bf16x8*)(Wp + (size_t)nt * 16 * EE);
    #pragma unroll
    for (int nt = 0; nt < 3; nt++) bN[nt] = *(const bf16x8*)(Wp + (size_t)nt * 16 * EE + 32);
    #pragma unroll
    for (int nt = 0; nt < 3; nt++) bT[nt] = bN[nt];
    __syncthreads();   // Xs visible

    #pragma unroll
    for (int k0 = 0; k0 < 12; k0++) {
        if (k0 < 10) {
            #pragma unroll
            for (int nt = 0; nt < 3; nt++)
                bT[nt] = *(const bf16x8*)(Wp + (size_t)nt * 16 * EE + (k0 + 2) * 32);
        }
        bf16x8 a0 = *(const bf16x8*)&Xs[fr][k0 * 32 + quad * 8];
        bf16x8 a1 = *(const bf16x8*)&Xs[16 + fr][k0 * 32 + quad * 8];
        #pragma unroll
        for (int nt = 0; nt < 3; nt++) {
            acc[0][nt] = __builtin_amdgcn_mfma_f32_16x16x32_bf16(a0, bC[nt], acc[0][nt], 0, 0, 0);
            acc[1][nt] = __builtin_amdgcn_mfma_f32_16x16x32_bf16(a1, bC[nt], acc[1][nt], 0, 0, 0);
        }
        #pragma unroll
        for (int nt = 0; nt < 3; nt++) { bC[nt] = bN[nt]; bN[nt] = bT[nt]; }
    }

    // epilogue: direct qbf writes + LDS stage for transposed qbfT
    const int bglob = m0 >> 11, t0 = m0 & 2047;
    #pragma unroll
    for (int nt = 0; nt < 3; nt++) {
        int nl = w * 48 + nt * 16 + fr;
        int n = blockIdx.y * 192 + nl;
        int h = n >> 6, d = n & 63;
        #pragma unroll
        for (int mt = 0; mt < 2; mt++)
            #pragma unroll
            for (int r = 0; r < 4; r++) {
                int ml = mt * 16 + quad * 4 + r;
                unsigned short bf = f2bf(acc[mt][nt][r]);
                qbf[((size_t)(bglob * HH + h) * TT + t0 + ml) * DD + d] = bf;
                Ts[ml][nl] = bf;
            }
    }
    __syncthreads();
    if (tid < 192) {
        int nl = tid;
        int n = blockIdx.y * 192 + nl;
        int h = n >> 6, d = n & 63;
        unsigned short tmp[32];
        #pragma unroll
        for (int i = 0; i < 32; i++) tmp[i] = Ts[i][nl];
        unsigned short* dst = qbfT + ((size_t)(bglob * HH + h) * DD + d) * TT + t0;
        *(uint4*)(dst)      = *(const uint4*)&tmp[0];
        *(uint4*)(dst + 8)  = *(const uint4*)&tmp[8];
        *(uint4*)(dst + 16) = *(const uint4*)&tmp[16];
        *(uint4*)(dst + 24) = *(const uint4*)&tmp[24];
    }
}

// ------------- MFMA flash attention (R24 restored -- 168.7us-total version) ---------
// Concurrent tile-pair: waves 0-3 own tile p, waves 4-7 own tile 63-p, sharing one
// K/V double-buffered stream (one staging pass, 1 barrier/iter). 24 waves/CU.
// R25's single-buffer + (512,8) VGPR squeeze SPILLED (VGPR=32, WRITE 30MB) -- do not
// force VGPR below ~68 here.
__global__ __launch_bounds__(512, 6) void k_attn(const unsigned short* __restrict__ qbf,
                                                 const unsigned short* __restrict__ qbfT,
                                                 unsigned short* __restrict__ cat)
{
    __shared__ unsigned short Ks[2][64][72];
    __shared__ unsigned short Vs[2][64][72];
    __shared__ unsigned short Ps[64][72];
    __shared__ float lsc[64];
    float (*Oc)[68] = (float(*)[68])&Ks[0][0][0];   // overlay 64x68x4 = 17408 <= 18432

    const int id = blockIdx.x;              // 0..767
    const int xcd = id & 7, j = id >> 3;
    const int bh = xcd * 3 + (j % 3);       // XCD-affine: 3 heads per XCD
    const int p = j / 3;                    // 0..31 ascending => longest blocks first
    const int bb = bh / HH, hh = bh % HH;
    const int tid = threadIdx.x;
    const int w = tid >> 6, lane = tid & 63;
    const int tg = w >> 2, wv = w & 3;      // tile group (0: tile p, 1: tile 63-p)
    const int qhalf = wv & 1, keyhalf = wv >> 1;
    const int fr = lane & 15, quad = lane >> 4;
    const int fc = quad * 8;
    const unsigned short* qb  = qbf  + (size_t)bh * TT * DD;
    const unsigned short* qtb = qbfT + (size_t)bh * DD * TT;
    const int lr = tid >> 3, lc = (tid & 7) * 8;   // 512-thr staging: 1 uint4 K + 1 V
    const float EXSC = 0.18033688011112042f;       // 0.125 * log2(e)

    const int tile = tg ? (63 - p) : p;
    const int m0 = tile * 32;
    const int nkt = (tile >> 1) + 1;        // this tile group's iteration count
    const int nktB = ((63 - p) >> 1) + 1;   // block-wide iteration count (max of pair)

    // ---- prologue: stage K/V tile 0 + load Q frags (direct, coalesced) ----
    {
        uint4 kr0 = *(const uint4*)(qb + (size_t)lr * DD + lc);
        uint4 vr0 = *(const uint4*)(qtb + (size_t)lr * TT + lc);
        *(uint4*)&Ks[0][lr][lc] = kr0;
        *(uint4*)&Vs[0][lr][lc] = vr0;
    }
    const unsigned short* qp = qb + (size_t)(m0 + qhalf * 16 + fr) * DD + fc;
    const bf16x8 qA0 = *(const bf16x8*)(qp);
    const bf16x8 qA1 = *(const bf16x8*)(qp + 32);
    __syncthreads();   // buf0 visible

    f32x4 accO[4];
    #pragma unroll
    for (int dt = 0; dt < 4; dt++) accO[dt] = (f32x4){0.f, 0.f, 0.f, 0.f};
    float ls[4] = {0.f, 0.f, 0.f, 0.f};
    const int rowbase = m0 + qhalf * 16 + quad * 4;
    const int prow = tg * 32 + qhalf * 16 + quad * 4;   // row in shared Ps/Oc/lsc space

    uint4 kr, vr;
    for (int kt = 0; kt < nktB; kt++) {
        const int cur = kt & 1;
        const int s0 = kt * 64;
        if (kt < nktB - 1) {   // prefetch next K/V tile into regs (full-iter cover)
            kr = *(const uint4*)(qb + (size_t)(s0 + 64 + lr) * DD + lc);
            vr = *(const uint4*)(qtb + (size_t)lr * TT + s0 + 64 + lc);
        }

        if (kt < nkt) {        // tile-p waves park here once past their diagonal
            f32x4 S[2];
            #pragma unroll
            for (int nt = 0; nt < 2; nt++) {
                f32x4 acc = (f32x4){0.f, 0.f, 0.f, 0.f};
                bf16x8 b0 = *(const bf16x8*)&Ks[cur][keyhalf * 32 + nt * 16 + fr][fc];
                acc = __builtin_amdgcn_mfma_f32_16x16x32_bf16(qA0, b0, acc, 0, 0, 0);
                bf16x8 b1 = *(const bf16x8*)&Ks[cur][keyhalf * 32 + nt * 16 + fr][fc + 32];
                acc = __builtin_amdgcn_mfma_f32_16x16x32_bf16(qA1, b1, acc, 0, 0, 0);
                S[nt] = acc;
            }

            const bool edge = (kt == nkt - 1);
            #pragma unroll
            for (int nt = 0; nt < 2; nt++) {
                const int col = keyhalf * 32 + nt * 16 + fr;
                float pv[4];
                if (edge) {
                    const int jg = s0 + col;
                    #pragma unroll
                    for (int r = 0; r < 4; r++) {
                        float s = S[nt][r];
                        pv[r] = (jg <= rowbase + r && s != 0.0f)
                                ? __builtin_amdgcn_exp2f(s * EXSC) : 0.0f;
                        ls[r] += pv[r];
                    }
                } else {       // fully below diagonal: no causal compare needed
                    #pragma unroll
                    for (int r = 0; r < 4; r++) {
                        float s = S[nt][r];
                        pv[r] = (s != 0.0f) ? __builtin_amdgcn_exp2f(s * EXSC) : 0.0f;
                        ls[r] += pv[r];
                    }
                }
                unsigned int pk0 = cvtpk(pv[0], pv[1]);
                unsigned int pk1 = cvtpk(pv[2], pv[3]);
                Ps[prow + 0][col] = (unsigned short)(pk0);
                Ps[prow + 1][col] = (unsigned short)(pk0 >> 16);
                Ps[prow + 2][col] = (unsigned short)(pk1);
                Ps[prow + 3][col] = (unsigned short)(pk1 >> 16);
            }

            // P exchange is intra-wave (own tg/qhalf/keyhalf quadrant): no barrier
            bf16x8 pA = *(const bf16x8*)&Ps[tg * 32 + qhalf * 16 + fr][keyhalf * 32 + fc];
            #pragma unroll
            for (int dt = 0; dt < 4; dt++) {
                bf16x8 v0 = *(const bf16x8*)&Vs[cur][dt * 16 + fr][keyhalf * 32 + fc];
                accO[dt] = __builtin_amdgcn_mfma_f32_16x16x32_bf16(pA, v0, accO[dt], 0, 0, 0);
            }
        }

        if (kt < nktB - 1) {
            *(uint4*)&Ks[cur ^ 1][lr][lc] = kr;
            *(uint4*)&Vs[cur ^ 1][lr][lc] = vr;
            __syncthreads();   // single barrier per iteration (R20 invariant)
        }
    }

    __syncthreads();   // final-iter LDS reads complete before Oc-overlay write
    #pragma unroll
    for (int r = 0; r < 4; r++) {
        #pragma unroll
        for (int o = 1; o < 16; o <<= 1) ls[r] += __shfl_xor(ls[r], o, 64);
    }
    if (keyhalf == 1) {
        #pragma unroll
        for (int dt = 0; dt < 4; dt++)
            #pragma unroll
            for (int r = 0; r < 4; r++)
                Oc[prow + r][dt * 16 + fr] = accO[dt][r];
        if (fr == 0) {
            #pragma unroll
            for (int r = 0; r < 4; r++) lsc[prow + r] = ls[r];
        }
    }
    __syncthreads();
    if (keyhalf == 0) {
        float il[4];
        #pragma unroll
        for (int r = 0; r < 4; r++) il[r] = 1.0f / (ls[r] + lsc[prow + r]);
        #pragma unroll
        for (int dt = 0; dt < 4; dt++) {
            #pragma unroll
            for (int r = 0; r < 4; r++) {
                float o = accO[dt][r] + Oc[prow + r][dt * 16 + fr];
                int t = rowbase + r;
                cat[((size_t)bb * TT + t) * EE + hh * DD + dt * 16 + fr] =
                    f2bf(o * il[r]);
            }
        }
    }
}

// ------------- fused proj+LN1 + FFN1 + FFN2+LN2 (R23, unchanged) --------------------
__global__ __launch_bounds__(512, 2) void k_ffn(const unsigned short* __restrict__ catb,
                                                const unsigned short* __restrict__ wob,
                                                const float* __restrict__ bo,
                                                const float* __restrict__ x,
                                                const float* __restrict__ g1,
                                                const float* __restrict__ be1,
                                                const unsigned short* __restrict__ w1b,
                                                const float* __restrict__ b1,
                                                const unsigned short* __restrict__ w2b,
                                                const float* __restrict__ b2,
                                                const float* __restrict__ g2,
                                                const float* __restrict__ be2,
                                                float* __restrict__ out)
{
    __shared__ unsigned short X1s[32][392];
    __shared__ unsigned short H1s[32][392];
    __shared__ float ssum[32][8];
    __shared__ float ssq[32][8];
    const int tid = threadIdx.x;
    const int w = tid >> 6, lane = tid & 63;
    const int fr = lane & 15, quad = lane >> 4;
    const int m0 = blockIdx.x * 32;
    const int n0 = w * 48;

    f32x4 acc[2][3];
    bf16x8 bC[3], bN[3], bT[3];
    const unsigned short* Wp1 = w1b + (size_t)(n0 + fr) * EE + quad * 8;
    const unsigned short* Wp2 = w2b + (size_t)(n0 + fr) * EE + quad * 8;

    // ================= GEMM1: proj = catb @ Wo^T (2 m-tiles) =================
    {
        const unsigned short* Ap0 = catb + (size_t)(m0 + fr) * EE + quad * 8;
        const unsigned short* Ap1 = Ap0 + 16 * EE;
        const unsigned short* Wp = wob + (size_t)(n0 + fr) * EE + quad * 8;
        #pragma unroll
        for (int mt = 0; mt < 2; mt++)
            #pragma unroll
            for (int nt = 0; nt < 3; nt++) acc[mt][nt] = (f32x4){0.f, 0.f, 0.f, 0.f};
        #pragma unroll
        for (int nt = 0; nt < 3; nt++) bC[nt] = *(const bf16x8*)(Wp + (size_t)nt * 16 * EE);
        #pragma unroll
        for (int nt = 0; nt < 3; nt++) bN[nt] = *(const bf16x8*)(Wp + (size_t)nt * 16 * EE + 32);
        #pragma unroll
        for (int nt = 0; nt < 3; nt++) bT[nt] = bN[nt];
        bf16x8 aC0 = *(const bf16x8*)(Ap0);
        bf16x8 aC1 = *(const bf16x8*)(Ap1);
        bf16x8 aN0 = *(const bf16x8*)(Ap0 + 32);
        bf16x8 aN1 = *(const bf16x8*)(Ap1 + 32);
        bf16x8 aT0 = aN0, aT1 = aN1;
        #pragma unroll
        for (int k0 = 0; k0 < 12; k0++) {
            if (k0 < 10) {
                #pragma unroll
                for (int nt = 0; nt < 3; nt++)
                    bT[nt] = *(const bf16x8*)(Wp + (size_t)nt * 16 * EE + (k0 + 2) * 32);
                aT0 = *(const bf16x8*)(Ap0 + (k0 + 2) * 32);
                aT1 = *(const bf16x8*)(Ap1 + (k0 + 2) * 32);
            }
            #pragma unroll
            for (int nt = 0; nt < 3; nt++) {
                acc[0][nt] = __builtin_amdgcn_mfma_f32_16x16x32_bf16(aC0, bC[nt], acc[0][nt], 0, 0, 0);
                acc[1][nt] = __builtin_amdgcn_mfma_f32_16x16x32_bf16(aC1, bC[nt], acc[1][nt], 0, 0, 0);
            }
            aC0 = aN0; aC1 = aN1; aN0 = aT0; aN1 = aT1;
            #pragma unroll
            for (int nt = 0; nt < 3; nt++) { bC[nt] = bN[nt]; bN[nt] = bT[nt]; }
        }
    }
    // early prefetch of GEMM2's first two weight stages (overlaps LN1 VALU)
    #pragma unroll
    for (int nt = 0; nt < 3; nt++) bC[nt] = *(const bf16x8*)(Wp1 + (size_t)nt * 16 * EE);
    #pragma unroll
    for (int nt = 0; nt < 3; nt++) bN[nt] = *(const bf16x8*)(Wp1 + (size_t)nt * 16 * EE + 32);
    // + bo + resid(x) -> LN1 stats
    {
        float s1[2][4] = {{0.f,0.f,0.f,0.f},{0.f,0.f,0.f,0.f}};
        float s2[2][4] = {{0.f,0.f,0.f,0.f},{0.f,0.f,0.f,0.f}};
        #pragma unroll
        for (int nt = 0; nt < 3; nt++) {
            int n = n0 + nt * 16 + fr;
            float bv = bo[n];
            #pragma unroll
            for (int mt = 0; mt < 2; mt++)
                #pragma unroll
                for (int r = 0; r < 4; r++) {
                    float v = acc[mt][nt][r] + bv
                            + x[(size_t)(m0 + mt * 16 + quad * 4 + r) * EE + n];
                    acc[mt][nt][r] = v;
                    s1[mt][r] += v;
                    s2[mt][r] += v * v;
                }
        }
        #pragma unroll
        for (int mt = 0; mt < 2; mt++)
            #pragma unroll
            for (int r = 0; r < 4; r++) {
                #pragma unroll
                for (int o = 1; o < 16; o <<= 1) {
                    s1[mt][r] += __shfl_xor(s1[mt][r], o, 64);
                    s2[mt][r] += __shfl_xor(s2[mt][r], o, 64);
                }
            }
        if (fr == 0) {
            #pragma unroll
            for (int mt = 0; mt < 2; mt++)
                #pragma unroll
                for (int r = 0; r < 4; r++) {
                    ssum[mt * 16 + quad * 4 + r][w] = s1[mt][r];
                    ssq [mt * 16 + quad * 4 + r][w] = s2[mt][r];
                }
        }
    }
    __syncthreads();
    {
        #pragma unroll
        for (int mt = 0; mt < 2; mt++) {
            float mu[4], rs[4];
            #pragma unroll
            for (int r = 0; r < 4; r++) {
                int row = mt * 16 + quad * 4 + r;
                float t1 = 0.f, t2 = 0.f;
                #pragma unroll
                for (int q = 0; q < 8; q++) { t1 += ssum[row][q]; t2 += ssq[row][q]; }
                mu[r] = t1 * (1.0f / EE);
                float var = t2 * (1.0f / EE) - mu[r] * mu[r];
                rs[r] = rsqrtf(var + 1e-5f);
            }
            #pragma unroll
            for (int nt = 0; nt < 3; nt++) {
                int n = n0 + nt * 16 + fr;
                float gv = g1[n], bev = be1[n];
                #pragma unroll
                for (int r = 0; r < 4; r++) {
                    float v = (acc[mt][nt][r] - mu[r]) * rs[r] * gv + bev;
                    X1s[mt * 16 + quad * 4 + r][n] = f2bf(v);
                }
            }
        }
    }
    __syncthreads();

    // ================= GEMM2: h1 = relu(x1 @ W1^T + b1) =================
    {
        #pragma unroll
        for (int mt = 0; mt < 2; mt++)
            #pragma unroll
            for (int nt = 0; nt < 3; nt++) acc[mt][nt] = (f32x4){0.f, 0.f, 0.f, 0.f};
        #pragma unroll
        for (int nt = 0; nt < 3; nt++) bT[nt] = bN[nt];
        #pragma unroll
        for (int k0 = 0; k0 < 12; k0++) {
            if (k0 < 10) {
                #pragma unroll
                for (int nt = 0; nt < 3; nt++)
                    bT[nt] = *(const bf16x8*)(Wp1 + (size_t)nt * 16 * EE + (k0 + 2) * 32);
            }
            bf16x8 a0 = *(const bf16x8*)&X1s[fr][k0 * 32 + quad * 8];
            bf16x8 a1 = *(const bf16x8*)&X1s[16 + fr][k0 * 32 + quad * 8];
            #pragma unroll
            for (int nt = 0; nt < 3; nt++) {
                acc[0][nt] = __builtin_amdgcn_mfma_f32_16x16x32_bf16(a0, bC[nt], acc[0][nt], 0, 0, 0);
                acc[1][nt] = __builtin_amdgcn_mfma_f32_16x16x32_bf16(a1, bC[nt], acc[1][nt], 0, 0, 0);
            }
            #pragma unroll
            for (int nt = 0; nt < 3; nt++) { bC[nt] = bN[nt]; bN[nt] = bT[nt]; }
        }
        // early prefetch of GEMM3's first two weight stages (overlaps relu/store VALU)
        #pragma unroll
        for (int nt = 0; nt < 3; nt++) bC[nt] = *(const bf16x8*)(Wp2 + (size_t)nt * 16 * EE);
        #pragma unroll
        for (int nt = 0; nt < 3; nt++) bN[nt] = *(const bf16x8*)(Wp2 + (size_t)nt * 16 * EE + 32);
        #pragma unroll
        for (int nt = 0; nt < 3; nt++) {
            int n = n0 + nt * 16 + fr;
            float bv = b1[n];
            #pragma unroll
            for (int mt = 0; mt < 2; mt++)
                #pragma unroll
                for (int r = 0; r < 4; r++)
                    H1s[mt * 16 + quad * 4 + r][n] = f2bf(fmaxf(acc[mt][nt][r] + bv, 0.0f));
        }
    }
    __syncthreads();

    // ================= GEMM3: ff = h1 @ W2^T + b2; LN2(x1 + ff) -> out =================
    {
        #pragma unroll
        for (int mt = 0; mt < 2; mt++)
            #pragma unroll
            for (int nt = 0; nt < 3; nt++) acc[mt][nt] = (f32x4){0.f, 0.f, 0.f, 0.f};
        #pragma unroll
        for (int nt = 0; nt < 3; nt++) bT[nt] = bN[nt];
        #pragma unroll
        for (int k0 = 0; k0 < 12; k0++) {
            if (k0 < 10) {
                #pragma unroll
                for (int nt = 0; nt < 3; nt++)
                    bT[nt] = *(const bf16x8*)(Wp2 + (size_t)nt * 16 * EE + (k0 + 2) * 32);
            }
            bf16x8 a0 = *(const bf16x8*)&H1s[fr][k0 * 32 + quad * 8];
            bf16x8 a1 = *(const bf16x8*)&H1s[16 + fr][k0 * 32 + quad * 8];
            #pragma unroll
            for (int nt = 0; nt < 3; nt++) {
                acc[0][nt] = __builtin_amdgcn_mfma_f32_16x16x32_bf16(a0, bC[nt], acc[0][nt], 0, 0, 0);
                acc[1][nt] = __builtin_amdgcn_mfma_f32_16x16x32_bf16(a1, bC[nt], acc[1][nt], 0, 0, 0);
            }
            #pragma unroll
            for (int nt = 0; nt < 3; nt++) { bC[nt] = bN[nt]; bN[nt] = bT[nt]; }
        }
    }
    {
        float s1[2][4] = {{0.f,0.f,0.f,0.f},{0.f,0.f,0.f,0.f}};
        float s2[2][4] = {{0.f,0.f,0.f,0.f},{0.f,0.f,0.f,0.f}};
        #pragma unroll
        for (int nt = 0; nt < 3; nt++) {
            int n = n0 + nt * 16 + fr;
            float bv = b2[n];
            #pragma unroll
            for (int mt = 0; mt < 2; mt++)
                #pragma unroll
                for (int r = 0; r < 4; r++) {
                    float v = acc[mt][nt][r] + bv + bf2f(X1s[mt * 16 + quad * 4 + r][n]);
                    acc[mt][nt][r] = v;
                    s1[mt][r] += v;
                    s2[mt][r] += v * v;
                }
        }
        #pragma unroll
        for (int mt = 0; mt < 2; mt++)
            #pragma unroll
            for (int r = 0; r < 4; r++) {
                #pragma unroll
                for (int o = 1; o < 16; o <<= 1) {
                    s1[mt][r] += __shfl_xor(s1[mt][r], o, 64);
                    s2[mt][r] += __shfl_xor(s2[mt][r], o, 64);
                }
            }
        if (fr == 0) {
            #pragma unroll
            for (int mt = 0; mt < 2; mt++)
                #pragma unroll
                for (int r = 0; r < 4; r++) {
                    ssum[mt * 16 + quad * 4 + r][w] = s1[mt][r];
                    ssq [mt * 16 + quad * 4 + r][w] = s2[mt][r];
                }
        }
    }
    __syncthreads();
    {
        #pragma unroll
        for (int mt = 0; mt < 2; mt++) {
            float mu[4], rs[4];
            #pragma unroll
            for (int r = 0; r < 4; r++) {
                int row = mt * 16 + quad * 4 + r;
                float u1 = 0.f, u2 = 0.f;
                #pragma unroll
                for (int q = 0; q < 8; q++) { u1 += ssum[row][q]; u2 += ssq[row][q]; }
                mu[r] = u1 * (1.0f / EE);
                float var = u2 * (1.0f / EE) - mu[r] * mu[r];
                rs[r] = rsqrtf(var + 1e-5f);
            }
            #pragma unroll
            for (int nt = 0; nt < 3; nt++) {
                int n = n0 + nt * 16 + fr;
                float gv = g2[n], bev = be2[n];
                #pragma unroll
                for (int r = 0; r < 4; r++)
                    out[(size_t)(m0 + mt * 16 + quad * 4 + r) * EE + n] =
                        (acc[mt][nt][r] - mu[r]) * rs[r] * gv + bev;
            }
        }
    }
}

extern "C" void kernel_launch(void* const* d_in, const int* in_sizes, int n_in,
                              void* d_out, int out_size, void* d_ws, size_t ws_size,
                              hipStream_t stream) {
    (void)in_sizes; (void)n_in; (void)out_size; (void)ws_size;
    const float* x   = (const float*)d_in[0];
    const float* Wq  = (const float*)d_in[1];
    const float* Wo  = (const float*)d_in[2];
    const float* bo  = (const float*)d_in[3];
    const float* W1  = (const float*)d_in[4];
    const float* b1  = (const float*)d_in[5];
    const float* W2  = (const float*)d_in[6];
    const float* b2  = (const float*)d_in[7];
    const float* g1  = (const float*)d_in[8];
    const float* be1 = (const float*)d_in[9];
    const float* g2  = (const float*)d_in[10];
    const float* be2 = (const float*)d_in[11];
    float* out = (float*)d_out;

    float* ws = (float*)d_ws;
    const size_t SZ = (size_t)MM * EE;    // 3,145,728 elems / region (12.6 MB fp32)
    float* S1 = ws + SZ;                   // qbf + qbfT (bf16, fills region exactly)
    float* S2 = ws + 2 * SZ;               // catb (bf16)
    float* S3 = ws + 3 * SZ;               // weight bf16 copies

    unsigned short* qbf  = (unsigned short*)S1;
    unsigned short* qbfT = qbf + (size_t)BB * HH * TT * DD;   // AFTER all of qbf!
    unsigned short* catb = (unsigned short*)S2;
    unsigned short* wqb  = (unsigned short*)S3;
    unsigned short* wob  = wqb + (size_t)EE * EE;
    unsigned short* w1b  = wob + (size_t)EE * EE;
    unsigned short* w2b  = w1b + (size_t)EE * EE;

    k_cvt<<<dim3(4 * 144), dim3(256), 0, stream>>>(Wq, Wo, W1, W2, wqb, wob, w1b, w2b);
    k_qgemm<<<dim3(MM / 32, 2), dim3(256), 0, stream>>>(x, wqb, qbf, qbfT);
    k_attn<<<dim3(768), dim3(512), 0, stream>>>(qbf, qbfT, catb);
    k_ffn<<<dim3(MM / 32), dim3(512), 0, stream>>>(catb, wob, bo, x, g1, be1,
                                                   w1b, b1, w2b, b2, g2, be2, out);
}

// Round 9
// 166.669 us; speedup vs baseline: 1.1187x; 1.0202x over previous
//
#include <hip/hip_runtime.h>
#include <math.h>

#define BB 4
#define TT 2048
#define EE 384
#define HH 6
#define DD 64
#define MM (BB*TT)   // 8192 tokens

typedef __attribute__((ext_vector_type(8))) short bf16x8;
typedef __attribute__((ext_vector_type(4))) float f32x4;

__device__ __forceinline__ unsigned short f2bf(float f) {
    unsigned int u = __float_as_uint(f);
    u = (u + 0x7FFFu + ((u >> 16) & 1u)) >> 16;   // RNE
    return (unsigned short)u;
}
__device__ __forceinline__ float bf2f(unsigned short u) {
    return __uint_as_float(((unsigned int)u) << 16);
}
__device__ __forceinline__ unsigned int pk2(float a, float b) {
    return (unsigned int)f2bf(a) | ((unsigned int)f2bf(b) << 16);
}
// HW packed fp32->bf16 (RNE) -- 1 VALU op for 2 values (no builtin; inline asm)
__device__ __forceinline__ unsigned int cvtpk(float lo, float hi) {
    unsigned int r;
    asm("v_cvt_pk_bf16_f32 %0, %1, %2" : "=v"(r) : "v"(lo), "v"(hi));
    return r;
}

// ------------- fp32 -> bf16 conversion: WEIGHTS ONLY (4 x 144 blocks) ----------------
__global__ __launch_bounds__(256) void k_cvt(const float* __restrict__ wq,
                                             const float* __restrict__ wo,
                                             const float* __restrict__ w1,
                                             const float* __restrict__ w2,
                                             unsigned short* __restrict__ wqb,
                                             unsigned short* __restrict__ wob,
                                             unsigned short* __restrict__ w1b,
                                             unsigned short* __restrict__ w2b)
{
    int wi = blockIdx.x / 144, off = (blockIdx.x % 144) * 256;
    const float* s4[4] = {wq, wo, w1, w2};
    unsigned short* d4[4] = {wqb, wob, w1b, w2b};
    const float* src = s4[wi]; unsigned short* dst = d4[wi];
    int i = off + threadIdx.x;
    float4 v = ((const float4*)src)[i];
    uint2 o; o.x = pk2(v.x, v.y); o.y = pk2(v.z, v.w);
    ((uint2*)dst)[i] = o;
}

// ------------- q-GEMM (R27: bounds back to (256,2) -- grid is 2 blocks/CU max;
// R26's (256,4) could not create a 3rd/4th block and only tightened VGPR) -----------
__global__ __launch_bounds__(256, 2) void k_qgemm(const float* __restrict__ x,
                                                  const unsigned short* __restrict__ W,
                                                  unsigned short* __restrict__ qbf,
                                                  unsigned short* __restrict__ qbfT)
{
    __shared__ unsigned short Xs[32][396];
    __shared__ unsigned short Ts[32][200];
    const int tid = threadIdx.x;
    const int w = tid >> 6, lane = tid & 63;
    const int fr = lane & 15, quad = lane >> 4;
    const int m0 = blockIdx.x * 32;
    const int n0 = blockIdx.y * 192 + w * 48;
    const unsigned short* Wp = W + (size_t)(n0 + fr) * EE + quad * 8;

    // ---- stage + convert A tile (32 x 384) ----
    {
        const float* xp = x + (size_t)m0 * EE;
        #pragma unroll
        for (int it = 0; it < 12; it++) {
            int idx = it * 1024 + tid * 4;
            int row = idx / EE, col = idx % EE;
            float4 v = *(const float4*)(xp + idx);
            uint2 o; o.x = pk2(v.x, v.y); o.y = pk2(v.z, v.w);
            *(uint2*)&Xs[row][col] = o;
        }
    }

    f32x4 acc[2][3];
    bf16x8 bC[3], bN[3], bT[3];
    #pragma unroll
    for (int mt = 0; mt < 2; mt++)
        #pragma unroll
        for (int nt = 0; nt < 3; nt++) acc[mt][nt] = (f32x4){0.f, 0.f, 0.f, 0.f};
    #pragma unroll
    for (int nt = 0; nt < 3; nt++) bC[nt] = *(const bf16x8*)(Wp + (size_t)nt * 16 * EE);
    #pragma unroll
    for (int nt = 0; nt < 3; nt++) bN[nt] = *(const bf16x8*)(Wp + (size_t)nt * 16 * EE + 32);
    #pragma unroll
    for (int nt = 0; nt < 3; nt++) bT[nt] = bN[nt];
    __syncthreads();   // Xs visible

    #pragma unroll
    for (int k0 = 0; k0 < 12; k0++) {
        if (k0 < 10) {
            #pragma unroll
            for (int nt = 0; nt < 3; nt++)
                bT[nt] = *(const bf16x8*)(Wp + (size_t)nt * 16 * EE + (k0 + 2) * 32);
        }
        bf16x8 a0 = *(const bf16x8*)&Xs[fr][k0 * 32 + quad * 8];
        bf16x8 a1 = *(const bf16x8*)&Xs[16 + fr][k0 * 32 + quad * 8];
        #pragma unroll
        for (int nt = 0; nt < 3; nt++) {
            acc[0][nt] = __builtin_amdgcn_mfma_f32_16x16x32_bf16(a0, bC[nt], acc[0][nt], 0, 0, 0);
            acc[1][nt] = __builtin_amdgcn_mfma_f32_16x16x32_bf16(a1, bC[nt], acc[1][nt], 0, 0, 0);
        }
        #pragma unroll
        for (int nt = 0; nt < 3; nt++) { bC[nt] = bN[nt]; bN[nt] = bT[nt]; }
    }

    // epilogue: direct qbf writes + LDS stage for transposed qbfT
    const int bglob = m0 >> 11, t0 = m0 & 2047;
    #pragma unroll
    for (int nt = 0; nt < 3; nt++) {
        int nl = w * 48 + nt * 16 + fr;
        int n = blockIdx.y * 192 + nl;
        int h = n >> 6, d = n & 63;
        #pragma unroll
        for (int mt = 0; mt < 2; mt++)
            #pragma unroll
            for (int r = 0; r < 4; r++) {
                int ml = mt * 16 + quad * 4 + r;
                unsigned short bf = f2bf(acc[mt][nt][r]);
                qbf[((size_t)(bglob * HH + h) * TT + t0 + ml) * DD + d] = bf;
                Ts[ml][nl] = bf;
            }
    }
    __syncthreads();
    if (tid < 192) {
        int nl = tid;
        int n = blockIdx.y * 192 + nl;
        int h = n >> 6, d = n & 63;
        unsigned short tmp[32];
        #pragma unroll
        for (int i = 0; i < 32; i++) tmp[i] = Ts[i][nl];
        unsigned short* dst = qbfT + ((size_t)(bglob * HH + h) * DD + d) * TT + t0;
        *(uint4*)(dst)      = *(const uint4*)&tmp[0];
        *(uint4*)(dst + 8)  = *(const uint4*)&tmp[8];
        *(uint4*)(dst + 16) = *(const uint4*)&tmp[16];
        *(uint4*)(dst + 24) = *(const uint4*)&tmp[24];
    }
}

// ------------- MFMA flash attention (R24, unchanged -- best measured) ----------------
// Concurrent tile-pair: waves 0-3 own tile p, waves 4-7 own tile 63-p, sharing one
// K/V double-buffered stream (one staging pass, 1 barrier/iter). 24 waves/CU.
// R25's single-buffer + (512,8) VGPR squeeze SPILLED (VGPR=32, WRITE 30MB) -- do not
// force VGPR below ~68 here.
__global__ __launch_bounds__(512, 6) void k_attn(const unsigned short* __restrict__ qbf,
                                                 const unsigned short* __restrict__ qbfT,
                                                 unsigned short* __restrict__ cat)
{
    __shared__ unsigned short Ks[2][64][72];
    __shared__ unsigned short Vs[2][64][72];
    __shared__ unsigned short Ps[64][72];
    __shared__ float lsc[64];
    float (*Oc)[68] = (float(*)[68])&Ks[0][0][0];   // overlay 64x68x4 = 17408 <= 18432

    const int id = blockIdx.x;              // 0..767
    const int xcd = id & 7, j = id >> 3;
    const int bh = xcd * 3 + (j % 3);       // XCD-affine: 3 heads per XCD
    const int p = j / 3;                    // 0..31 ascending => longest blocks first
    const int bb = bh / HH, hh = bh % HH;
    const int tid = threadIdx.x;
    const int w = tid >> 6, lane = tid & 63;
    const int tg = w >> 2, wv = w & 3;      // tile group (0: tile p, 1: tile 63-p)
    const int qhalf = wv & 1, keyhalf = wv >> 1;
    const int fr = lane & 15, quad = lane >> 4;
    const int fc = quad * 8;
    const unsigned short* qb  = qbf  + (size_t)bh * TT * DD;
    const unsigned short* qtb = qbfT + (size_t)bh * DD * TT;
    const int lr = tid >> 3, lc = (tid & 7) * 8;   // 512-thr staging: 1 uint4 K + 1 V
    const float EXSC = 0.18033688011112042f;       // 0.125 * log2(e)

    const int tile = tg ? (63 - p) : p;
    const int m0 = tile * 32;
    const int nkt = (tile >> 1) + 1;        // this tile group's iteration count
    const int nktB = ((63 - p) >> 1) + 1;   // block-wide iteration count (max of pair)

    // ---- prologue: stage K/V tile 0 + load Q frags (direct, coalesced) ----
    {
        uint4 kr0 = *(const uint4*)(qb + (size_t)lr * DD + lc);
        uint4 vr0 = *(const uint4*)(qtb + (size_t)lr * TT + lc);
        *(uint4*)&Ks[0][lr][lc] = kr0;
        *(uint4*)&Vs[0][lr][lc] = vr0;
    }
    const unsigned short* qp = qb + (size_t)(m0 + qhalf * 16 + fr) * DD + fc;
    const bf16x8 qA0 = *(const bf16x8*)(qp);
    const bf16x8 qA1 = *(const bf16x8*)(qp + 32);
    __syncthreads();   // buf0 visible

    f32x4 accO[4];
    #pragma unroll
    for (int dt = 0; dt < 4; dt++) accO[dt] = (f32x4){0.f, 0.f, 0.f, 0.f};
    float ls[4] = {0.f, 0.f, 0.f, 0.f};
    const int rowbase = m0 + qhalf * 16 + quad * 4;
    const int prow = tg * 32 + qhalf * 16 + quad * 4;   // row in shared Ps/Oc/lsc space

    uint4 kr, vr;
    for (int kt = 0; kt < nktB; kt++) {
        const int cur = kt & 1;
        const int s0 = kt * 64;
        if (kt < nktB - 1) {   // prefetch next K/V tile into regs (full-iter cover)
            kr = *(const uint4*)(qb + (size_t)(s0 + 64 + lr) * DD + lc);
            vr = *(const uint4*)(qtb + (size_t)lr * TT + s0 + 64 + lc);
        }

        if (kt < nkt) {        // tile-p waves park here once past their diagonal
            f32x4 S[2];
            #pragma unroll
            for (int nt = 0; nt < 2; nt++) {
                f32x4 acc = (f32x4){0.f, 0.f, 0.f, 0.f};
                bf16x8 b0 = *(const bf16x8*)&Ks[cur][keyhalf * 32 + nt * 16 + fr][fc];
                acc = __builtin_amdgcn_mfma_f32_16x16x32_bf16(qA0, b0, acc, 0, 0, 0);
                bf16x8 b1 = *(const bf16x8*)&Ks[cur][keyhalf * 32 + nt * 16 + fr][fc + 32];
                acc = __builtin_amdgcn_mfma_f32_16x16x32_bf16(qA1, b1, acc, 0, 0, 0);
                S[nt] = acc;
            }

            const bool edge = (kt == nkt - 1);
            #pragma unroll
            for (int nt = 0; nt < 2; nt++) {
                const int col = keyhalf * 32 + nt * 16 + fr;
                float pv[4];
                if (edge) {
                    const int jg = s0 + col;
                    #pragma unroll
                    for (int r = 0; r < 4; r++) {
                        float s = S[nt][r];
                        pv[r] = (jg <= rowbase + r && s != 0.0f)
                                ? __builtin_amdgcn_exp2f(s * EXSC) : 0.0f;
                        ls[r] += pv[r];
                    }
                } else {       // fully below diagonal: no causal compare needed
                    #pragma unroll
                    for (int r = 0; r < 4; r++) {
                        float s = S[nt][r];
                        pv[r] = (s != 0.0f) ? __builtin_amdgcn_exp2f(s * EXSC) : 0.0f;
                        ls[r] += pv[r];
                    }
                }
                unsigned int pk0 = cvtpk(pv[0], pv[1]);
                unsigned int pk1 = cvtpk(pv[2], pv[3]);
                Ps[prow + 0][col] = (unsigned short)(pk0);
                Ps[prow + 1][col] = (unsigned short)(pk0 >> 16);
                Ps[prow + 2][col] = (unsigned short)(pk1);
                Ps[prow + 3][col] = (unsigned short)(pk1 >> 16);
            }

            // P exchange is intra-wave (own tg/qhalf/keyhalf quadrant): no barrier
            bf16x8 pA = *(const bf16x8*)&Ps[tg * 32 + qhalf * 16 + fr][keyhalf * 32 + fc];
            #pragma unroll
            for (int dt = 0; dt < 4; dt++) {
                bf16x8 v0 = *(const bf16x8*)&Vs[cur][dt * 16 + fr][keyhalf * 32 + fc];
                accO[dt] = __builtin_amdgcn_mfma_f32_16x16x32_bf16(pA, v0, accO[dt], 0, 0, 0);
            }
        }

        if (kt < nktB - 1) {
            *(uint4*)&Ks[cur ^ 1][lr][lc] = kr;
            *(uint4*)&Vs[cur ^ 1][lr][lc] = vr;
            __syncthreads();   // single barrier per iteration (R20 invariant)
        }
    }

    __syncthreads();   // final-iter LDS reads complete before Oc-overlay write
    #pragma unroll
    for (int r = 0; r < 4; r++) {
        #pragma unroll
        for (int o = 1; o < 16; o <<= 1) ls[r] += __shfl_xor(ls[r], o, 64);
    }
    if (keyhalf == 1) {
        #pragma unroll
        for (int dt = 0; dt < 4; dt++)
            #pragma unroll
            for (int r = 0; r < 4; r++)
                Oc[prow + r][dt * 16 + fr] = accO[dt][r];
        if (fr == 0) {
            #pragma unroll
            for (int r = 0; r < 4; r++) lsc[prow + r] = ls[r];
        }
    }
    __syncthreads();
    if (keyhalf == 0) {
        float il[4];
        #pragma unroll
        for (int r = 0; r < 4; r++) il[r] = 1.0f / (ls[r] + lsc[prow + r]);
        #pragma unroll
        for (int dt = 0; dt < 4; dt++) {
            #pragma unroll
            for (int r = 0; r < 4; r++) {
                float o = accO[dt][r] + Oc[prow + r][dt * 16 + fr];
                int t = rowbase + r;
                cat[((size_t)bb * TT + t) * EE + hh * DD + dt * 16 + fr] =
                    f2bf(o * il[r]);
            }
        }
    }
}

// ------------- fused proj+LN1 + FFN1 + FFN2+LN2 (R27) -------------------------------
// Structural fix: GEMM1's A-tile (catb) was loaded redundantly by ALL 8 waves
// (waves differ only in n0 -> same A) via per-wave rolling global loads whose
// dist-2 cover couldn't hide catb's HBM/L3 latency and which poisoned the in-order
// vmcnt waits for the interleaved weight loads. Now staged ONCE cooperatively into
// the H1s buffer (dead until GEMM2's epilogue, which is after a barrier -- zero LDS
// growth), read from LDS like GEMM2/3. Also: x-residual + bo hoisted to registers
// at kernel start -- they drain at the staging barrier, so LN1 hits registers.
__global__ __launch_bounds__(512, 2) void k_ffn(const unsigned short* __restrict__ catb,
                                                const unsigned short* __restrict__ wob,
                                                const float* __restrict__ bo,
                                                const float* __restrict__ x,
                                                const float* __restrict__ g1,
                                                const float* __restrict__ be1,
                                                const unsigned short* __restrict__ w1b,
                                                const float* __restrict__ b1,
                                                const unsigned short* __restrict__ w2b,
                                                const float* __restrict__ b2,
                                                const float* __restrict__ g2,
                                                const float* __restrict__ be2,
                                                float* __restrict__ out)
{
    __shared__ unsigned short X1s[32][392];
    __shared__ unsigned short H1s[32][392];
    __shared__ float ssum[32][8];
    __shared__ float ssq[32][8];
    const int tid = threadIdx.x;
    const int w = tid >> 6, lane = tid & 63;
    const int fr = lane & 15, quad = lane >> 4;
    const int m0 = blockIdx.x * 32;
    const int n0 = w * 48;

    f32x4 acc[2][3];
    bf16x8 bC[3], bN[3], bT[3];
    const unsigned short* Wp1 = w1b + (size_t)(n0 + fr) * EE + quad * 8;
    const unsigned short* Wp2 = w2b + (size_t)(n0 + fr) * EE + quad * 8;

    // ---- stage catb A-tile -> H1s (cooperative, coalesced, once per block) ----
    {
        const unsigned short* cp = catb + (size_t)m0 * EE;
        #pragma unroll
        for (int c = 0; c < 3; c++) {
            int idx = c * 4096 + tid * 8;
            int row = idx / EE, col = idx % EE;
            *(uint4*)&H1s[row][col] = *(const uint4*)(cp + idx);
        }
    }
    // ---- hoist x residual + bo to registers (drain at staging barrier) ----
    float xr[2][3][4];
    float bor[3];
    #pragma unroll
    for (int nt = 0; nt < 3; nt++) {
        int n = n0 + nt * 16 + fr;
        bor[nt] = bo[n];
        #pragma unroll
        for (int mt = 0; mt < 2; mt++)
            #pragma unroll
            for (int r = 0; r < 4; r++)
                xr[mt][nt][r] = x[(size_t)(m0 + mt * 16 + quad * 4 + r) * EE + n];
    }

    // ================= GEMM1: proj = catb @ Wo^T (A from LDS) =================
    {
        const unsigned short* Wp = wob + (size_t)(n0 + fr) * EE + quad * 8;
        #pragma unroll
        for (int mt = 0; mt < 2; mt++)
            #pragma unroll
            for (int nt = 0; nt < 3; nt++) acc[mt][nt] = (f32x4){0.f, 0.f, 0.f, 0.f};
        #pragma unroll
        for (int nt = 0; nt < 3; nt++) bC[nt] = *(const bf16x8*)(Wp + (size_t)nt * 16 * EE);
        #pragma unroll
        for (int nt = 0; nt < 3; nt++) bN[nt] = *(const bf16x8*)(Wp + (size_t)nt * 16 * EE + 32);
        #pragma unroll
        for (int nt = 0; nt < 3; nt++) bT[nt] = bN[nt];
        __syncthreads();   // H1s A-tile visible (also drains xr/bor loads)
        #pragma unroll
        for (int k0 = 0; k0 < 12; k0++) {
            if (k0 < 10) {
                #pragma unroll
                for (int nt = 0; nt < 3; nt++)
                    bT[nt] = *(const bf16x8*)(Wp + (size_t)nt * 16 * EE + (k0 + 2) * 32);
            }
            bf16x8 a0 = *(const bf16x8*)&H1s[fr][k0 * 32 + quad * 8];
            bf16x8 a1 = *(const bf16x8*)&H1s[16 + fr][k0 * 32 + quad * 8];
            #pragma unroll
            for (int nt = 0; nt < 3; nt++) {
                acc[0][nt] = __builtin_amdgcn_mfma_f32_16x16x32_bf16(a0, bC[nt], acc[0][nt], 0, 0, 0);
                acc[1][nt] = __builtin_amdgcn_mfma_f32_16x16x32_bf16(a1, bC[nt], acc[1][nt], 0, 0, 0);
            }
            #pragma unroll
            for (int nt = 0; nt < 3; nt++) { bC[nt] = bN[nt]; bN[nt] = bT[nt]; }
        }
    }
    // early prefetch of GEMM2's first two weight stages (overlaps LN1 VALU)
    #pragma unroll
    for (int nt = 0; nt < 3; nt++) bC[nt] = *(const bf16x8*)(Wp1 + (size_t)nt * 16 * EE);
    #pragma unroll
    for (int nt = 0; nt < 3; nt++) bN[nt] = *(const bf16x8*)(Wp1 + (size_t)nt * 16 * EE + 32);
    // + bo + resid(x) -> LN1 stats (x/bo already in registers)
    {
        float s1[2][4] = {{0.f,0.f,0.f,0.f},{0.f,0.f,0.f,0.f}};
        float s2[2][4] = {{0.f,0.f,0.f,0.f},{0.f,0.f,0.f,0.f}};
        #pragma unroll
        for (int nt = 0; nt < 3; nt++) {
            #pragma unroll
            for (int mt = 0; mt < 2; mt++)
                #pragma unroll
                for (int r = 0; r < 4; r++) {
                    float v = acc[mt][nt][r] + bor[nt] + xr[mt][nt][r];
                    acc[mt][nt][r] = v;
                    s1[mt][r] += v;
                    s2[mt][r] += v * v;
                }
        }
        #pragma unroll
        for (int mt = 0; mt < 2; mt++)
            #pragma unroll
            for (int r = 0; r < 4; r++) {
                #pragma unroll
                for (int o = 1; o < 16; o <<= 1) {
                    s1[mt][r] += __shfl_xor(s1[mt][r], o, 64);
                    s2[mt][r] += __shfl_xor(s2[mt][r], o, 64);
                }
            }
        if (fr == 0) {
            #pragma unroll
            for (int mt = 0; mt < 2; mt++)
                #pragma unroll
                for (int r = 0; r < 4; r++) {
                    ssum[mt * 16 + quad * 4 + r][w] = s1[mt][r];
                    ssq [mt * 16 + quad * 4 + r][w] = s2[mt][r];
                }
        }
    }
    __syncthreads();
    {
        #pragma unroll
        for (int mt = 0; mt < 2; mt++) {
            float mu[4], rs[4];
            #pragma unroll
            for (int r = 0; r < 4; r++) {
                int row = mt * 16 + quad * 4 + r;
                float t1 = 0.f, t2 = 0.f;
                #pragma unroll
                for (int q = 0; q < 8; q++) { t1 += ssum[row][q]; t2 += ssq[row][q]; }
                mu[r] = t1 * (1.0f / EE);
                float var = t2 * (1.0f / EE) - mu[r] * mu[r];
                rs[r] = rsqrtf(var + 1e-5f);
            }
            #pragma unroll
            for (int nt = 0; nt < 3; nt++) {
                int n = n0 + nt * 16 + fr;
                float gv = g1[n], bev = be1[n];
                #pragma unroll
                for (int r = 0; r < 4; r++) {
                    float v = (acc[mt][nt][r] - mu[r]) * rs[r] * gv + bev;
                    X1s[mt * 16 + quad * 4 + r][n] = f2bf(v);
                }
            }
        }
    }
    __syncthreads();

    // ================= GEMM2: h1 = relu(x1 @ W1^T + b1) =================
    {
        #pragma unroll
        for (int mt = 0; mt < 2; mt++)
            #pragma unroll
            for (int nt = 0; nt < 3; nt++) acc[mt][nt] = (f32x4){0.f, 0.f, 0.f, 0.f};
        #pragma unroll
        for (int nt = 0; nt < 3; nt++) bT[nt] = bN[nt];
        #pragma unroll
        for (int k0 = 0; k0 < 12; k0++) {
            if (k0 < 10) {
                #pragma unroll
                for (int nt = 0; nt < 3; nt++)
                    bT[nt] = *(const bf16x8*)(Wp1 + (size_t)nt * 16 * EE + (k0 + 2) * 32);
            }
            bf16x8 a0 = *(const bf16x8*)&X1s[fr][k0 * 32 + quad * 8];
            bf16x8 a1 = *(const bf16x8*)&X1s[16 + fr][k0 * 32 + quad * 8];
            #pragma unroll
            for (int nt = 0; nt < 3; nt++) {
                acc[0][nt] = __builtin_amdgcn_mfma_f32_16x16x32_bf16(a0, bC[nt], acc[0][nt], 0, 0, 0);
                acc[1][nt] = __builtin_amdgcn_mfma_f32_16x16x32_bf16(a1, bC[nt], acc[1][nt], 0, 0, 0);
            }
            #pragma unroll
            for (int nt = 0; nt < 3; nt++) { bC[nt] = bN[nt]; bN[nt] = bT[nt]; }
        }
        // early prefetch of GEMM3's first two weight stages (overlaps relu/store VALU)
        #pragma unroll
        for (int nt = 0; nt < 3; nt++) bC[nt] = *(const bf16x8*)(Wp2 + (size_t)nt * 16 * EE);
        #pragma unroll
        for (int nt = 0; nt < 3; nt++) bN[nt] = *(const bf16x8*)(Wp2 + (size_t)nt * 16 * EE + 32);
        __syncthreads();   // GEMM1's H1s A-reads complete before overwrite below
        #pragma unroll
        for (int nt = 0; nt < 3; nt++) {
            int n = n0 + nt * 16 + fr;
            float bv = b1[n];
            #pragma unroll
            for (int mt = 0; mt < 2; mt++)
                #pragma unroll
                for (int r = 0; r < 4; r++)
                    H1s[mt * 16 + quad * 4 + r][n] = f2bf(fmaxf(acc[mt][nt][r] + bv, 0.0f));
        }
    }
    __syncthreads();

    // ================= GEMM3: ff = h1 @ W2^T + b2; LN2(x1 + ff) -> out =================
    {
        #pragma unroll
        for (int mt = 0; mt < 2; mt++)
            #pragma unroll
            for (int nt = 0; nt < 3; nt++) acc[mt][nt] = (f32x4){0.f, 0.f, 0.f, 0.f};
        #pragma unroll
        for (int nt = 0; nt < 3; nt++) bT[nt] = bN[nt];
        #pragma unroll
        for (int k0 = 0; k0 < 12; k0++) {
            if (k0 < 10) {
                #pragma unroll
                for (int nt = 0; nt < 3; nt++)
                    bT[nt] = *(const bf16x8*)(Wp2 + (size_t)nt * 16 * EE + (k0 + 2) * 32);
            }
            bf16x8 a0 = *(const bf16x8*)&H1s[fr][k0 * 32 + quad * 8];
            bf16x8 a1 = *(const bf16x8*)&H1s[16 + fr][k0 * 32 + quad * 8];
            #pragma unroll
            for (int nt = 0; nt < 3; nt++) {
                acc[0][nt] = __builtin_amdgcn_mfma_f32_16x16x32_bf16(a0, bC[nt], acc[0][nt], 0, 0, 0);
                acc[1][nt] = __builtin_amdgcn_mfma_f32_16x16x32_bf16(a1, bC[nt], acc[1][nt], 0, 0, 0);
            }
            #pragma unroll
            for (int nt = 0; nt < 3; nt++) { bC[nt] = bN[nt]; bN[nt] = bT[nt]; }
        }
    }
    {
        float s1[2][4] = {{0.f,0.f,0.f,0.f},{0.f,0.f,0.f,0.f}};
        float s2[2][4] = {{0.f,0.f,0.f,0.f},{0.f,0.f,0.f,0.f}};
        #pragma unroll
        for (int nt = 0; nt < 3; nt++) {
            int n = n0 + nt * 16 + fr;
            float bv = b2[n];
            #pragma unroll
            for (int mt = 0; mt < 2; mt++)
                #pragma unroll
                for (int r = 0; r < 4; r++) {
                    float v = acc[mt][nt][r] + bv + bf2f(X1s[mt * 16 + quad * 4 + r][n]);
                    acc[mt][nt][r] = v;
                    s1[mt][r] += v;
                    s2[mt][r] += v * v;
                }
        }
        #pragma unroll
        for (int mt = 0; mt < 2; mt++)
            #pragma unroll
            for (int r = 0; r < 4; r++) {
                #pragma unroll
                for (int o = 1; o < 16; o <<= 1) {
                    s1[mt][r] += __shfl_xor(s1[mt][r], o, 64);
                    s2[mt][r] += __shfl_xor(s2[mt][r], o, 64);
                }
            }
        if (fr == 0) {
            #pragma unroll
            for (int mt = 0; mt < 2; mt++)
                #pragma unroll
                for (int r = 0; r < 4; r++) {
                    ssum[mt * 16 + quad * 4 + r][w] = s1[mt][r];
                    ssq [mt * 16 + quad * 4 + r][w] = s2[mt][r];
                }
        }
    }
    __syncthreads();
    {
        #pragma unroll
        for (int mt = 0; mt < 2; mt++) {
            float mu[4], rs[4];
            #pragma unroll
            for (int r = 0; r < 4; r++) {
                int row = mt * 16 + quad * 4 + r;
                float u1 = 0.f, u2 = 0.f;
                #pragma unroll
                for (int q = 0; q < 8; q++) { u1 += ssum[row][q]; u2 += ssq[row][q]; }
                mu[r] = u1 * (1.0f / EE);
                float var = u2 * (1.0f / EE) - mu[r] * mu[r];
                rs[r] = rsqrtf(var + 1e-5f);
            }
            #pragma unroll
            for (int nt = 0; nt < 3; nt++) {
                int n = n0 + nt * 16 + fr;
                float gv = g2[n], bev = be2[n];
                #pragma unroll
                for (int r = 0; r < 4; r++)
                    out[(size_t)(m0 + mt * 16 + quad * 4 + r) * EE + n] =
                        (acc[mt][nt][r] - mu[r]) * rs[r] * gv + bev;
            }
        }
    }
}

extern "C" void kernel_launch(void* const* d_in, const int* in_sizes, int n_in,
                              void* d_out, int out_size, void* d_ws, size_t ws_size,
                              hipStream_t stream) {
    (void)in_sizes; (void)n_in; (void)out_size; (void)ws_size;
    const float* x   = (const float*)d_in[0];
    const float* Wq  = (const float*)d_in[1];
    const float* Wo  = (const float*)d_in[2];
    const float* bo  = (const float*)d_in[3];
    const float* W1  = (const float*)d_in[4];
    const float* b1  = (const float*)d_in[5];
    const float* W2  = (const float*)d_in[6];
    const float* b2  = (const float*)d_in[7];
    const float* g1  = (const float*)d_in[8];
    const float* be1 = (const float*)d_in[9];
    const float* g2  = (const float*)d_in[10];
    const float* be2 = (const float*)d_in[11];
    float* out = (float*)d_out;

    float* ws = (float*)d_ws;
    const size_t SZ = (size_t)MM * EE;    // 3,145,728 elems / region (12.6 MB fp32)
    float* S1 = ws + SZ;                   // qbf + qbfT (bf16, fills region exactly)
    float* S2 = ws + 2 * SZ;               // catb (bf16)
    float* S3 = ws + 3 * SZ;               // weight bf16 copies

    unsigned short* qbf  = (unsigned short*)S1;
    unsigned short* qbfT = qbf + (size_t)BB * HH * TT * DD;   // AFTER all of qbf!
    unsigned short* catb = (unsigned short*)S2;
    unsigned short* wqb  = (unsigned short*)S3;
    unsigned short* wob  = wqb + (size_t)EE * EE;
    unsigned short* w1b  = wob + (size_t)EE * EE;
    unsigned short* w2b  = w1b + (size_t)EE * EE;

    k_cvt<<<dim3(4 * 144), dim3(256), 0, stream>>>(Wq, Wo, W1, W2, wqb, wob, w1b, w2b);
    k_qgemm<<<dim3(MM / 32, 2), dim3(256), 0, stream>>>(x, wqb, qbf, qbfT);
    k_attn<<<dim3(768), dim3(256 * 2), 0, stream>>>(qbf, qbfT, catb);
    k_ffn<<<dim3(MM / 32), dim3(512), 0, stream>>>(catb, wob, bo, x, g1, be1,
                                                   w1b, b1, w2b, b2, g2, be2, out);
}

// Round 10
// 165.657 us; speedup vs baseline: 1.1255x; 1.0061x over previous
//
#include <hip/hip_runtime.h>
#include <math.h>

#define BB 4
#define TT 2048
#define EE 384
#define HH 6
#define DD 64
#define MM (BB*TT)   // 8192 tokens

typedef __attribute__((ext_vector_type(8))) short bf16x8;
typedef __attribute__((ext_vector_type(4))) float f32x4;

__device__ __forceinline__ unsigned short f2bf(float f) {
    unsigned int u = __float_as_uint(f);
    u = (u + 0x7FFFu + ((u >> 16) & 1u)) >> 16;   // RNE
    return (unsigned short)u;
}
__device__ __forceinline__ float bf2f(unsigned short u) {
    return __uint_as_float(((unsigned int)u) << 16);
}
__device__ __forceinline__ unsigned int pk2(float a, float b) {
    return (unsigned int)f2bf(a) | ((unsigned int)f2bf(b) << 16);
}
// HW packed fp32->bf16 (RNE) -- 1 VALU op for 2 values (no builtin; inline asm)
__device__ __forceinline__ unsigned int cvtpk(float lo, float hi) {
    unsigned int r;
    asm("v_cvt_pk_bf16_f32 %0, %1, %2" : "=v"(r) : "v"(lo), "v"(hi));
    return r;
}

// ------------- fp32 -> bf16 conversion: WEIGHTS ONLY (4 x 144 blocks) ----------------
__global__ __launch_bounds__(256) void k_cvt(const float* __restrict__ wq,
                                             const float* __restrict__ wo,
                                             const float* __restrict__ w1,
                                             const float* __restrict__ w2,
                                             unsigned short* __restrict__ wqb,
                                             unsigned short* __restrict__ wob,
                                             unsigned short* __restrict__ w1b,
                                             unsigned short* __restrict__ w2b)
{
    int wi = blockIdx.x / 144, off = (blockIdx.x % 144) * 256;
    const float* s4[4] = {wq, wo, w1, w2};
    unsigned short* d4[4] = {wqb, wob, w1b, w2b};
    const float* src = s4[wi]; unsigned short* dst = d4[wi];
    int i = off + threadIdx.x;
    float4 v = ((const float4*)src)[i];
    uint2 o; o.x = pk2(v.x, v.y); o.y = pk2(v.z, v.w);
    ((uint2*)dst)[i] = o;
}

// ------------- q-GEMM (R28: coalesced qbf epilogue via Ts) ---------------------------
// The qbf write was 24 scalar 2B stores/thread (scattered, poor write-combining, on
// the epilogue critical path). The 32x192 tile already lives in Ts for the qbfT
// transpose -- so qbf is now written from Ts as 768 contiguous uint4 stores
// (3/thread, 16B-coalesced within each row's 128B head segment). Bytes identical.
__global__ __launch_bounds__(256, 2) void k_qgemm(const float* __restrict__ x,
                                                  const unsigned short* __restrict__ W,
                                                  unsigned short* __restrict__ qbf,
                                                  unsigned short* __restrict__ qbfT)
{
    __shared__ unsigned short Xs[32][396];
    __shared__ unsigned short Ts[32][200];
    const int tid = threadIdx.x;
    const int w = tid >> 6, lane = tid & 63;
    const int fr = lane & 15, quad = lane >> 4;
    const int m0 = blockIdx.x * 32;
    const int n0 = blockIdx.y * 192 + w * 48;
    const unsigned short* Wp = W + (size_t)(n0 + fr) * EE + quad * 8;

    // ---- stage + convert A tile (32 x 384) ----
    {
        const float* xp = x + (size_t)m0 * EE;
        #pragma unroll
        for (int it = 0; it < 12; it++) {
            int idx = it * 1024 + tid * 4;
            int row = idx / EE, col = idx % EE;
            float4 v = *(const float4*)(xp + idx);
            uint2 o; o.x = pk2(v.x, v.y); o.y = pk2(v.z, v.w);
            *(uint2*)&Xs[row][col] = o;
        }
    }

    f32x4 acc[2][3];
    bf16x8 bC[3], bN[3], bT[3];
    #pragma unroll
    for (int mt = 0; mt < 2; mt++)
        #pragma unroll
        for (int nt = 0; nt < 3; nt++) acc[mt][nt] = (f32x4){0.f, 0.f, 0.f, 0.f};
    #pragma unroll
    for (int nt = 0; nt < 3; nt++) bC[nt] = *(const bf16x8*)(Wp + (size_t)nt * 16 * EE);
    #pragma unroll
    for (int nt = 0; nt < 3; nt++) bN[nt] = *(const bf16x8*)(Wp + (size_t)nt * 16 * EE + 32);
    #pragma unroll
    for (int nt = 0; nt < 3; nt++) bT[nt] = bN[nt];
    __syncthreads();   // Xs visible

    #pragma unroll
    for (int k0 = 0; k0 < 12; k0++) {
        if (k0 < 10) {
            #pragma unroll
            for (int nt = 0; nt < 3; nt++)
                bT[nt] = *(const bf16x8*)(Wp + (size_t)nt * 16 * EE + (k0 + 2) * 32);
        }
        bf16x8 a0 = *(const bf16x8*)&Xs[fr][k0 * 32 + quad * 8];
        bf16x8 a1 = *(const bf16x8*)&Xs[16 + fr][k0 * 32 + quad * 8];
        #pragma unroll
        for (int nt = 0; nt < 3; nt++) {
            acc[0][nt] = __builtin_amdgcn_mfma_f32_16x16x32_bf16(a0, bC[nt], acc[0][nt], 0, 0, 0);
            acc[1][nt] = __builtin_amdgcn_mfma_f32_16x16x32_bf16(a1, bC[nt], acc[1][nt], 0, 0, 0);
        }
        #pragma unroll
        for (int nt = 0; nt < 3; nt++) { bC[nt] = bN[nt]; bN[nt] = bT[nt]; }
    }

    // epilogue: stage tile into Ts only (both qbf and qbfT written from Ts)
    const int bglob = m0 >> 11, t0 = m0 & 2047;
    #pragma unroll
    for (int nt = 0; nt < 3; nt++) {
        int nl = w * 48 + nt * 16 + fr;
        #pragma unroll
        for (int mt = 0; mt < 2; mt++)
            #pragma unroll
            for (int r = 0; r < 4; r++) {
                int ml = mt * 16 + quad * 4 + r;
                Ts[ml][nl] = f2bf(acc[mt][nt][r]);
            }
    }
    __syncthreads();
    // coalesced qbf: 32 rows x 3 heads x 8 uint4 = 768 uint4 stores, 3 per thread
    #pragma unroll
    for (int it = 0; it < 3; it++) {
        int idx = it * 256 + tid;
        int row = idx / 24, piece = idx % 24;
        int head = piece >> 3, q = piece & 7;
        int hg = blockIdx.y * 3 + head;
        unsigned short* dst = qbf + ((size_t)(bglob * HH + hg) * TT + t0 + row) * DD + q * 8;
        *(uint4*)dst = *(const uint4*)&Ts[row][head * 64 + q * 8];
    }
    if (tid < 192) {
        int nl = tid;
        int n = blockIdx.y * 192 + nl;
        int h = n >> 6, d = n & 63;
        unsigned short tmp[32];
        #pragma unroll
        for (int i = 0; i < 32; i++) tmp[i] = Ts[i][nl];
        unsigned short* dst = qbfT + ((size_t)(bglob * HH + h) * DD + d) * TT + t0;
        *(uint4*)(dst)      = *(const uint4*)&tmp[0];
        *(uint4*)(dst + 8)  = *(const uint4*)&tmp[8];
        *(uint4*)(dst + 16) = *(const uint4*)&tmp[16];
        *(uint4*)(dst + 24) = *(const uint4*)&tmp[24];
    }
}

// ------------- MFMA flash attention (R24 structure + Ps pad 76) ----------------------
// Concurrent tile-pair: waves 0-3 own tile p, waves 4-7 own tile 63-p, sharing one
// K/V double-buffered stream (one staging pass, 1 barrier/iter). 24 waves/CU.
// R28: Ps stride 72->76 (152B/row): the 8 scalar P-writes/iter go from 4-way bank
// conflict (16 banks) to conflict-free (quad*24+fr/2 covers all 32 banks). LDS
// 45.8KB -> still 3 blocks/CU. R25's (512,8) VGPR squeeze SPILLED -- keep 68 VGPR.
__global__ __launch_bounds__(512, 6) void k_attn(const unsigned short* __restrict__ qbf,
                                                 const unsigned short* __restrict__ qbfT,
                                                 unsigned short* __restrict__ cat)
{
    __shared__ unsigned short Ks[2][64][72];
    __shared__ unsigned short Vs[2][64][72];
    __shared__ unsigned short Ps[64][76];
    __shared__ float lsc[64];
    float (*Oc)[68] = (float(*)[68])&Ks[0][0][0];   // overlay 64x68x4 = 17408 <= 18432

    const int id = blockIdx.x;              // 0..767
    const int xcd = id & 7, j = id >> 3;
    const int bh = xcd * 3 + (j % 3);       // XCD-affine: 3 heads per XCD
    const int p = j / 3;                    // 0..31 ascending => longest blocks first
    const int bb = bh / HH, hh = bh % HH;
    const int tid = threadIdx.x;
    const int w = tid >> 6, lane = tid & 63;
    const int tg = w >> 2, wv = w & 3;      // tile group (0: tile p, 1: tile 63-p)
    const int qhalf = wv & 1, keyhalf = wv >> 1;
    const int fr = lane & 15, quad = lane >> 4;
    const int fc = quad * 8;
    const unsigned short* qb  = qbf  + (size_t)bh * TT * DD;
    const unsigned short* qtb = qbfT + (size_t)bh * DD * TT;
    const int lr = tid >> 3, lc = (tid & 7) * 8;   // 512-thr staging: 1 uint4 K + 1 V
    const float EXSC = 0.18033688011112042f;       // 0.125 * log2(e)

    const int tile = tg ? (63 - p) : p;
    const int m0 = tile * 32;
    const int nkt = (tile >> 1) + 1;        // this tile group's iteration count
    const int nktB = ((63 - p) >> 1) + 1;   // block-wide iteration count (max of pair)

    // ---- prologue: stage K/V tile 0 + load Q frags (direct, coalesced) ----
    {
        uint4 kr0 = *(const uint4*)(qb + (size_t)lr * DD + lc);
        uint4 vr0 = *(const uint4*)(qtb + (size_t)lr * TT + lc);
        *(uint4*)&Ks[0][lr][lc] = kr0;
        *(uint4*)&Vs[0][lr][lc] = vr0;
    }
    const unsigned short* qp = qb + (size_t)(m0 + qhalf * 16 + fr) * DD + fc;
    const bf16x8 qA0 = *(const bf16x8*)(qp);
    const bf16x8 qA1 = *(const bf16x8*)(qp + 32);
    __syncthreads();   // buf0 visible

    f32x4 accO[4];
    #pragma unroll
    for (int dt = 0; dt < 4; dt++) accO[dt] = (f32x4){0.f, 0.f, 0.f, 0.f};
    float ls[4] = {0.f, 0.f, 0.f, 0.f};
    const int rowbase = m0 + qhalf * 16 + quad * 4;
    const int prow = tg * 32 + qhalf * 16 + quad * 4;   // row in shared Ps/Oc/lsc space

    uint4 kr, vr;
    for (int kt = 0; kt < nktB; kt++) {
        const int cur = kt & 1;
        const int s0 = kt * 64;
        if (kt < nktB - 1) {   // prefetch next K/V tile into regs (full-iter cover)
            kr = *(const uint4*)(qb + (size_t)(s0 + 64 + lr) * DD + lc);
            vr = *(const uint4*)(qtb + (size_t)lr * TT + s0 + 64 + lc);
        }

        if (kt < nkt) {        // tile-p waves park here once past their diagonal
            f32x4 S[2];
            #pragma unroll
            for (int nt = 0; nt < 2; nt++) {
                f32x4 acc = (f32x4){0.f, 0.f, 0.f, 0.f};
                bf16x8 b0 = *(const bf16x8*)&Ks[cur][keyhalf * 32 + nt * 16 + fr][fc];
                acc = __builtin_amdgcn_mfma_f32_16x16x32_bf16(qA0, b0, acc, 0, 0, 0);
                bf16x8 b1 = *(const bf16x8*)&Ks[cur][keyhalf * 32 + nt * 16 + fr][fc + 32];
                acc = __builtin_amdgcn_mfma_f32_16x16x32_bf16(qA1, b1, acc, 0, 0, 0);
                S[nt] = acc;
            }

            const bool edge = (kt == nkt - 1);
            #pragma unroll
            for (int nt = 0; nt < 2; nt++) {
                const int col = keyhalf * 32 + nt * 16 + fr;
                float pv[4];
                if (edge) {
                    const int jg = s0 + col;
                    #pragma unroll
                    for (int r = 0; r < 4; r++) {
                        float s = S[nt][r];
                        pv[r] = (jg <= rowbase + r && s != 0.0f)
                                ? __builtin_amdgcn_exp2f(s * EXSC) : 0.0f;
                        ls[r] += pv[r];
                    }
                } else {       // fully below diagonal: no causal compare needed
                    #pragma unroll
                    for (int r = 0; r < 4; r++) {
                        float s = S[nt][r];
                        pv[r] = (s != 0.0f) ? __builtin_amdgcn_exp2f(s * EXSC) : 0.0f;
                        ls[r] += pv[r];
                    }
                }
                unsigned int pk0 = cvtpk(pv[0], pv[1]);
                unsigned int pk1 = cvtpk(pv[2], pv[3]);
                Ps[prow + 0][col] = (unsigned short)(pk0);
                Ps[prow + 1][col] = (unsigned short)(pk0 >> 16);
                Ps[prow + 2][col] = (unsigned short)(pk1);
                Ps[prow + 3][col] = (unsigned short)(pk1 >> 16);
            }

            // P exchange is intra-wave (own tg/qhalf/keyhalf quadrant): no barrier
            bf16x8 pA = *(const bf16x8*)&Ps[tg * 32 + qhalf * 16 + fr][keyhalf * 32 + fc];
            #pragma unroll
            for (int dt = 0; dt < 4; dt++) {
                bf16x8 v0 = *(const bf16x8*)&Vs[cur][dt * 16 + fr][keyhalf * 32 + fc];
                accO[dt] = __builtin_amdgcn_mfma_f32_16x16x32_bf16(pA, v0, accO[dt], 0, 0, 0);
            }
        }

        if (kt < nktB - 1) {
            *(uint4*)&Ks[cur ^ 1][lr][lc] = kr;
            *(uint4*)&Vs[cur ^ 1][lr][lc] = vr;
            __syncthreads();   // single barrier per iteration (R20 invariant)
        }
    }

    __syncthreads();   // final-iter LDS reads complete before Oc-overlay write
    #pragma unroll
    for (int r = 0; r < 4; r++) {
        #pragma unroll
        for (int o = 1; o < 16; o <<= 1) ls[r] += __shfl_xor(ls[r], o, 64);
    }
    if (keyhalf == 1) {
        #pragma unroll
        for (int dt = 0; dt < 4; dt++)
            #pragma unroll
            for (int r = 0; r < 4; r++)
                Oc[prow + r][dt * 16 + fr] = accO[dt][r];
        if (fr == 0) {
            #pragma unroll
            for (int r = 0; r < 4; r++) lsc[prow + r] = ls[r];
        }
    }
    __syncthreads();
    if (keyhalf == 0) {
        float il[4];
        #pragma unroll
        for (int r = 0; r < 4; r++) il[r] = 1.0f / (ls[r] + lsc[prow + r]);
        #pragma unroll
        for (int dt = 0; dt < 4; dt++) {
            #pragma unroll
            for (int r = 0; r < 4; r++) {
                float o = accO[dt][r] + Oc[prow + r][dt * 16 + fr];
                int t = rowbase + r;
                cat[((size_t)bb * TT + t) * EE + hh * DD + dt * 16 + fr] =
                    f2bf(o * il[r]);
            }
        }
    }
}

// ------------- fused proj+LN1 + FFN1 + FFN2+LN2 (R27, unchanged) --------------------
// GEMM1's A staged once cooperatively into H1s (dead until GEMM2 epilogue); x/bo
// hoisted to registers at kernel start (drain at the staging barrier).
__global__ __launch_bounds__(512, 2) void k_ffn(const unsigned short* __restrict__ catb,
                                                const unsigned short* __restrict__ wob,
                                                const float* __restrict__ bo,
                                                const float* __restrict__ x,
                                                const float* __restrict__ g1,
                                                const float* __restrict__ be1,
                                                const unsigned short* __restrict__ w1b,
                                                const float* __restrict__ b1,
                                                const unsigned short* __restrict__ w2b,
                                                const float* __restrict__ b2,
                                                const float* __restrict__ g2,
                                                const float* __restrict__ be2,
                                                float* __restrict__ out)
{
    __shared__ unsigned short X1s[32][392];
    __shared__ unsigned short H1s[32][392];
    __shared__ float ssum[32][8];
    __shared__ float ssq[32][8];
    const int tid = threadIdx.x;
    const int w = tid >> 6, lane = tid & 63;
    const int fr = lane & 15, quad = lane >> 4;
    const int m0 = blockIdx.x * 32;
    const int n0 = w * 48;

    f32x4 acc[2][3];
    bf16x8 bC[3], bN[3], bT[3];
    const unsigned short* Wp1 = w1b + (size_t)(n0 + fr) * EE + quad * 8;
    const unsigned short* Wp2 = w2b + (size_t)(n0 + fr) * EE + quad * 8;

    // ---- stage catb A-tile -> H1s (cooperative, coalesced, once per block) ----
    {
        const unsigned short* cp = catb + (size_t)m0 * EE;
        #pragma unroll
        for (int c = 0; c < 3; c++) {
            int idx = c * 4096 + tid * 8;
            int row = idx / EE, col = idx % EE;
            *(uint4*)&H1s[row][col] = *(const uint4*)(cp + idx);
        }
    }
    // ---- hoist x residual + bo to registers (drain at staging barrier) ----
    float xr[2][3][4];
    float bor[3];
    #pragma unroll
    for (int nt = 0; nt < 3; nt++) {
        int n = n0 + nt * 16 + fr;
        bor[nt] = bo[n];
        #pragma unroll
        for (int mt = 0; mt < 2; mt++)
            #pragma unroll
            for (int r = 0; r < 4; r++)
                xr[mt][nt][r] = x[(size_t)(m0 + mt * 16 + quad * 4 + r) * EE + n];
    }

    // ================= GEMM1: proj = catb @ Wo^T (A from LDS) =================
    {
        const unsigned short* Wp = wob + (size_t)(n0 + fr) * EE + quad * 8;
        #pragma unroll
        for (int mt = 0; mt < 2; mt++)
            #pragma unroll
            for (int nt = 0; nt < 3; nt++) acc[mt][nt] = (f32x4){0.f, 0.f, 0.f, 0.f};
        #pragma unroll
        for (int nt = 0; nt < 3; nt++) bC[nt] = *(const bf16x8*)(Wp + (size_t)nt * 16 * EE);
        #pragma unroll
        for (int nt = 0; nt < 3; nt++) bN[nt] = *(const bf16x8*)(Wp + (size_t)nt * 16 * EE + 32);
        #pragma unroll
        for (int nt = 0; nt < 3; nt++) bT[nt] = bN[nt];
        __syncthreads();   // H1s A-tile visible (also drains xr/bor loads)
        #pragma unroll
        for (int k0 = 0; k0 < 12; k0++) {
            if (k0 < 10) {
                #pragma unroll
                for (int nt = 0; nt < 3; nt++)
                    bT[nt] = *(const bf16x8*)(Wp + (size_t)nt * 16 * EE + (k0 + 2) * 32);
            }
            bf16x8 a0 = *(const bf16x8*)&H1s[fr][k0 * 32 + quad * 8];
            bf16x8 a1 = *(const bf16x8*)&H1s[16 + fr][k0 * 32 + quad * 8];
            #pragma unroll
            for (int nt = 0; nt < 3; nt++) {
                acc[0][nt] = __builtin_amdgcn_mfma_f32_16x16x32_bf16(a0, bC[nt], acc[0][nt], 0, 0, 0);
                acc[1][nt] = __builtin_amdgcn_mfma_f32_16x16x32_bf16(a1, bC[nt], acc[1][nt], 0, 0, 0);
            }
            #pragma unroll
            for (int nt = 0; nt < 3; nt++) { bC[nt] = bN[nt]; bN[nt] = bT[nt]; }
        }
    }
    // early prefetch of GEMM2's first two weight stages (overlaps LN1 VALU)
    #pragma unroll
    for (int nt = 0; nt < 3; nt++) bC[nt] = *(const bf16x8*)(Wp1 + (size_t)nt * 16 * EE);
    #pragma unroll
    for (int nt = 0; nt < 3; nt++) bN[nt] = *(const bf16x8*)(Wp1 + (size_t)nt * 16 * EE + 32);
    // + bo + resid(x) -> LN1 stats (x/bo already in registers)
    {
        float s1[2][4] = {{0.f,0.f,0.f,0.f},{0.f,0.f,0.f,0.f}};
        float s2[2][4] = {{0.f,0.f,0.f,0.f},{0.f,0.f,0.f,0.f}};
        #pragma unroll
        for (int nt = 0; nt < 3; nt++) {
            #pragma unroll
            for (int mt = 0; mt < 2; mt++)
                #pragma unroll
                for (int r = 0; r < 4; r++) {
                    float v = acc[mt][nt][r] + bor[nt] + xr[mt][nt][r];
                    acc[mt][nt][r] = v;
                    s1[mt][r] += v;
                    s2[mt][r] += v * v;
                }
        }
        #pragma unroll
        for (int mt = 0; mt < 2; mt++)
            #pragma unroll
            for (int r = 0; r < 4; r++) {
                #pragma unroll
                for (int o = 1; o < 16; o <<= 1) {
                    s1[mt][r] += __shfl_xor(s1[mt][r], o, 64);
                    s2[mt][r] += __shfl_xor(s2[mt][r], o, 64);
                }
            }
        if (fr == 0) {
            #pragma unroll
            for (int mt = 0; mt < 2; mt++)
                #pragma unroll
                for (int r = 0; r < 4; r++) {
                    ssum[mt * 16 + quad * 4 + r][w] = s1[mt][r];
                    ssq [mt * 16 + quad * 4 + r][w] = s2[mt][r];
                }
        }
    }
    __syncthreads();
    {
        #pragma unroll
        for (int mt = 0; mt < 2; mt++) {
            float mu[4], rs[4];
            #pragma unroll
            for (int r = 0; r < 4; r++) {
                int row = mt * 16 + quad * 4 + r;
                float t1 = 0.f, t2 = 0.f;
                #pragma unroll
                for (int q = 0; q < 8; q++) { t1 += ssum[row][q]; t2 += ssq[row][q]; }
                mu[r] = t1 * (1.0f / EE);
                float var = t2 * (1.0f / EE) - mu[r] * mu[r];
                rs[r] = rsqrtf(var + 1e-5f);
            }
            #pragma unroll
            for (int nt = 0; nt < 3; nt++) {
                int n = n0 + nt * 16 + fr;
                float gv = g1[n], bev = be1[n];
                #pragma unroll
                for (int r = 0; r < 4; r++) {
                    float v = (acc[mt][nt][r] - mu[r]) * rs[r] * gv + bev;
                    X1s[mt * 16 + quad * 4 + r][n] = f2bf(v);
                }
            }
        }
    }
    __syncthreads();

    // ================= GEMM2: h1 = relu(x1 @ W1^T + b1) =================
    {
        #pragma unroll
        for (int mt = 0; mt < 2; mt++)
            #pragma unroll
            for (int nt = 0; nt < 3; nt++) acc[mt][nt] = (f32x4){0.f, 0.f, 0.f, 0.f};
        #pragma unroll
        for (int nt = 0; nt < 3; nt++) bT[nt] = bN[nt];
        #pragma unroll
        for (int k0 = 0; k0 < 12; k0++) {
            if (k0 < 10) {
                #pragma unroll
                for (int nt = 0; nt < 3; nt++)
                    bT[nt] = *(const bf16x8*)(Wp1 + (size_t)nt * 16 * EE + (k0 + 2) * 32);
            }
            bf16x8 a0 = *(const bf16x8*)&X1s[fr][k0 * 32 + quad * 8];
            bf16x8 a1 = *(const bf16x8*)&X1s[16 + fr][k0 * 32 + quad * 8];
            #pragma unroll
            for (int nt = 0; nt < 3; nt++) {
                acc[0][nt] = __builtin_amdgcn_mfma_f32_16x16x32_bf16(a0, bC[nt], acc[0][nt], 0, 0, 0);
                acc[1][nt] = __builtin_amdgcn_mfma_f32_16x16x32_bf16(a1, bC[nt], acc[1][nt], 0, 0, 0);
            }
            #pragma unroll
            for (int nt = 0; nt < 3; nt++) { bC[nt] = bN[nt]; bN[nt] = bT[nt]; }
        }
        // early prefetch of GEMM3's first two weight stages (overlaps relu/store VALU)
        #pragma unroll
        for (int nt = 0; nt < 3; nt++) bC[nt] = *(const bf16x8*)(Wp2 + (size_t)nt * 16 * EE);
        #pragma unroll
        for (int nt = 0; nt < 3; nt++) bN[nt] = *(const bf16x8*)(Wp2 + (size_t)nt * 16 * EE + 32);
        __syncthreads();   // GEMM1's H1s A-reads complete before overwrite below
        #pragma unroll
        for (int nt = 0; nt < 3; nt++) {
            int n = n0 + nt * 16 + fr;
            float bv = b1[n];
            #pragma unroll
            for (int mt = 0; mt < 2; mt++)
                #pragma unroll
                for (int r = 0; r < 4; r++)
                    H1s[mt * 16 + quad * 4 + r][n] = f2bf(fmaxf(acc[mt][nt][r] + bv, 0.0f));
        }
    }
    __syncthreads();

    // ================= GEMM3: ff = h1 @ W2^T + b2; LN2(x1 + ff) -> out =================
    {
        #pragma unroll
        for (int mt = 0; mt < 2; mt++)
            #pragma unroll
            for (int nt = 0; nt < 3; nt++) acc[mt][nt] = (f32x4){0.f, 0.f, 0.f, 0.f};
        #pragma unroll
        for (int nt = 0; nt < 3; nt++) bT[nt] = bN[nt];
        #pragma unroll
        for (int k0 = 0; k0 < 12; k0++) {
            if (k0 < 10) {
                #pragma unroll
                for (int nt = 0; nt < 3; nt++)
                    bT[nt] = *(const bf16x8*)(Wp2 + (size_t)nt * 16 * EE + (k0 + 2) * 32);
            }
            bf16x8 a0 = *(const bf16x8*)&H1s[fr][k0 * 32 + quad * 8];
            bf16x8 a1 = *(const bf16x8*)&H1s[16 + fr][k0 * 32 + quad * 8];
            #pragma unroll
            for (int nt = 0; nt < 3; nt++) {
                acc[0][nt] = __builtin_amdgcn_mfma_f32_16x16x32_bf16(a0, bC[nt], acc[0][nt], 0, 0, 0);
                acc[1][nt] = __builtin_amdgcn_mfma_f32_16x16x32_bf16(a1, bC[nt], acc[1][nt], 0, 0, 0);
            }
            #pragma unroll
            for (int nt = 0; nt < 3; nt++) { bC[nt] = bN[nt]; bN[nt] = bT[nt]; }
        }
    }
    {
        float s1[2][4] = {{0.f,0.f,0.f,0.f},{0.f,0.f,0.f,0.f}};
        float s2[2][4] = {{0.f,0.f,0.f,0.f},{0.f,0.f,0.f,0.f}};
        #pragma unroll
        for (int nt = 0; nt < 3; nt++) {
            int n = n0 + nt * 16 + fr;
            float bv = b2[n];
            #pragma unroll
            for (int mt = 0; mt < 2; mt++)
                #pragma unroll
                for (int r = 0; r < 4; r++) {
                    float v = acc[mt][nt][r] + bv + bf2f(X1s[mt * 16 + quad * 4 + r][n]);
                    acc[mt][nt][r] = v;
                    s1[mt][r] += v;
                    s2[mt][r] += v * v;
                }
        }
        #pragma unroll
        for (int mt = 0; mt < 2; mt++)
            #pragma unroll
            for (int r = 0; r < 4; r++) {
                #pragma unroll
                for (int o = 1; o < 16; o <<= 1) {
                    s1[mt][r] += __shfl_xor(s1[mt][r], o, 64);
                    s2[mt][r] += __shfl_xor(s2[mt][r], o, 64);
                }
            }
        if (fr == 0) {
            #pragma unroll
            for (int mt = 0; mt < 2; mt++)
                #pragma unroll
                for (int r = 0; r < 4; r++) {
                    ssum[mt * 16 + quad * 4 + r][w] = s1[mt][r];
                    ssq [mt * 16 + quad * 4 + r][w] = s2[mt][r];
                }
        }
    }
    __syncthreads();
    {
        #pragma unroll
        for (int mt = 0; mt < 2; mt++) {
            float mu[4], rs[4];
            #pragma unroll
            for (int r = 0; r < 4; r++) {
                int row = mt * 16 + quad * 4 + r;
                float u1 = 0.f, u2 = 0.f;
                #pragma unroll
                for (int q = 0; q < 8; q++) { u1 += ssum[row][q]; u2 += ssq[row][q]; }
                mu[r] = u1 * (1.0f / EE);
                float var = u2 * (1.0f / EE) - mu[r] * mu[r];
                rs[r] = rsqrtf(var + 1e-5f);
            }
            #pragma unroll
            for (int nt = 0; nt < 3; nt++) {
                int n = n0 + nt * 16 + fr;
                float gv = g2[n], bev = be2[n];
                #pragma unroll
                for (int r = 0; r < 4; r++)
                    out[(size_t)(m0 + mt * 16 + quad * 4 + r) * EE + n] =
                        (acc[mt][nt][r] - mu[r]) * rs[r] * gv + bev;
            }
        }
    }
}

extern "C" void kernel_launch(void* const* d_in, const int* in_sizes, int n_in,
                              void* d_out, int out_size, void* d_ws, size_t ws_size,
                              hipStream_t stream) {
    (void)in_sizes; (void)n_in; (void)out_size; (void)ws_size;
    const float* x   = (const float*)d_in[0];
    const float* Wq  = (const float*)d_in[1];
    const float* Wo  = (const float*)d_in[2];
    const float* bo  = (const float*)d_in[3];
    const float* W1  = (const float*)d_in[4];
    const float* b1  = (const float*)d_in[5];
    const float* W2  = (const float*)d_in[6];
    const float* b2  = (const float*)d_in[7];
    const float* g1  = (const float*)d_in[8];
    const float* be1 = (const float*)d_in[9];
    const float* g2  = (const float*)d_in[10];
    const float* be2 = (const float*)d_in[11];
    float* out = (float*)d_out;

    float* ws = (float*)d_ws;
    const size_t SZ = (size_t)MM * EE;    // 3,145,728 elems / region (12.6 MB fp32)
    float* S1 = ws + SZ;                   // qbf + qbfT (bf16, fills region exactly)
    float* S2 = ws + 2 * SZ;               // catb (bf16)
    float* S3 = ws + 3 * SZ;               // weight bf16 copies

    unsigned short* qbf  = (unsigned short*)S1;
    unsigned short* qbfT = qbf + (size_t)BB * HH * TT * DD;   // AFTER all of qbf!
    unsigned short* catb = (unsigned short*)S2;
    unsigned short* wqb  = (unsigned short*)S3;
    unsigned short* wob  = wqb + (size_t)EE * EE;
    unsigned short* w1b  = wob + (size_t)EE * EE;
    unsigned short* w2b  = w1b + (size_t)EE * EE;

    k_cvt<<<dim3(4 * 144), dim3(256), 0, stream>>>(Wq, Wo, W1, W2, wqb, wob, w1b, w2b);
    k_qgemm<<<dim3(MM / 32, 2), dim3(256), 0, stream>>>(x, wqb, qbf, qbfT);
    k_attn<<<dim3(768), dim3(512), 0, stream>>>(qbf, qbfT, catb);
    k_ffn<<<dim3(MM / 32), dim3(512), 0, stream>>>(catb, wob, bo, x, g1, be1,
                                                   w1b, b1, w2b, b2, g2, be2, out);
}

// Round 11
// 164.787 us; speedup vs baseline: 1.1315x; 1.0053x over previous
//
#include <hip/hip_runtime.h>
#include <math.h>

#define BB 4
#define TT 2048
#define EE 384
#define HH 6
#define DD 64
#define MM (BB*TT)   // 8192 tokens

typedef __attribute__((ext_vector_type(8))) short bf16x8;
typedef __attribute__((ext_vector_type(4))) float f32x4;

__device__ __forceinline__ unsigned short f2bf(float f) {
    unsigned int u = __float_as_uint(f);
    u = (u + 0x7FFFu + ((u >> 16) & 1u)) >> 16;   // RNE
    return (unsigned short)u;
}
__device__ __forceinline__ float bf2f(unsigned short u) {
    return __uint_as_float(((unsigned int)u) << 16);
}
__device__ __forceinline__ unsigned int pk2(float a, float b) {
    return (unsigned int)f2bf(a) | ((unsigned int)f2bf(b) << 16);
}
// HW packed fp32->bf16 (RNE) -- 1 VALU op for 2 values (no builtin; inline asm)
__device__ __forceinline__ unsigned int cvtpk(float lo, float hi) {
    unsigned int r;
    asm("v_cvt_pk_bf16_f32 %0, %1, %2" : "=v"(r) : "v"(lo), "v"(hi));
    return r;
}

// ------------- fp32 -> bf16 conversion: WEIGHTS ONLY (4 x 144 blocks) ----------------
__global__ __launch_bounds__(256) void k_cvt(const float* __restrict__ wq,
                                             const float* __restrict__ wo,
                                             const float* __restrict__ w1,
                                             const float* __restrict__ w2,
                                             unsigned short* __restrict__ wqb,
                                             unsigned short* __restrict__ wob,
                                             unsigned short* __restrict__ w1b,
                                             unsigned short* __restrict__ w2b)
{
    int wi = blockIdx.x / 144, off = (blockIdx.x % 144) * 256;
    const float* s4[4] = {wq, wo, w1, w2};
    unsigned short* d4[4] = {wqb, wob, w1b, w2b};
    const float* src = s4[wi]; unsigned short* dst = d4[wi];
    int i = off + threadIdx.x;
    float4 v = ((const float4*)src)[i];
    uint2 o; o.x = pk2(v.x, v.y); o.y = pk2(v.z, v.w);
    ((uint2*)dst)[i] = o;
}

// ------------- q-GEMM (R28: coalesced qbf epilogue via Ts) ---------------------------
__global__ __launch_bounds__(256, 2) void k_qgemm(const float* __restrict__ x,
                                                  const unsigned short* __restrict__ W,
                                                  unsigned short* __restrict__ qbf,
                                                  unsigned short* __restrict__ qbfT)
{
    __shared__ unsigned short Xs[32][396];
    __shared__ unsigned short Ts[32][200];
    const int tid = threadIdx.x;
    const int w = tid >> 6, lane = tid & 63;
    const int fr = lane & 15, quad = lane >> 4;
    const int m0 = blockIdx.x * 32;
    const int n0 = blockIdx.y * 192 + w * 48;
    const unsigned short* Wp = W + (size_t)(n0 + fr) * EE + quad * 8;

    // ---- stage + convert A tile (32 x 384) ----
    {
        const float* xp = x + (size_t)m0 * EE;
        #pragma unroll
        for (int it = 0; it < 12; it++) {
            int idx = it * 1024 + tid * 4;
            int row = idx / EE, col = idx % EE;
            float4 v = *(const float4*)(xp + idx);
            uint2 o; o.x = pk2(v.x, v.y); o.y = pk2(v.z, v.w);
            *(uint2*)&Xs[row][col] = o;
        }
    }

    f32x4 acc[2][3];
    bf16x8 bC[3], bN[3], bT[3];
    #pragma unroll
    for (int mt = 0; mt < 2; mt++)
        #pragma unroll
        for (int nt = 0; nt < 3; nt++) acc[mt][nt] = (f32x4){0.f, 0.f, 0.f, 0.f};
    #pragma unroll
    for (int nt = 0; nt < 3; nt++) bC[nt] = *(const bf16x8*)(Wp + (size_t)nt * 16 * EE);
    #pragma unroll
    for (int nt = 0; nt < 3; nt++) bN[nt] = *(const bf16x8*)(Wp + (size_t)nt * 16 * EE + 32);
    #pragma unroll
    for (int nt = 0; nt < 3; nt++) bT[nt] = bN[nt];
    __syncthreads();   // Xs visible

    #pragma unroll
    for (int k0 = 0; k0 < 12; k0++) {
        if (k0 < 10) {
            #pragma unroll
            for (int nt = 0; nt < 3; nt++)
                bT[nt] = *(const bf16x8*)(Wp + (size_t)nt * 16 * EE + (k0 + 2) * 32);
        }
        bf16x8 a0 = *(const bf16x8*)&Xs[fr][k0 * 32 + quad * 8];
        bf16x8 a1 = *(const bf16x8*)&Xs[16 + fr][k0 * 32 + quad * 8];
        #pragma unroll
        for (int nt = 0; nt < 3; nt++) {
            acc[0][nt] = __builtin_amdgcn_mfma_f32_16x16x32_bf16(a0, bC[nt], acc[0][nt], 0, 0, 0);
            acc[1][nt] = __builtin_amdgcn_mfma_f32_16x16x32_bf16(a1, bC[nt], acc[1][nt], 0, 0, 0);
        }
        #pragma unroll
        for (int nt = 0; nt < 3; nt++) { bC[nt] = bN[nt]; bN[nt] = bT[nt]; }
    }

    // epilogue: stage tile into Ts only (both qbf and qbfT written from Ts)
    const int bglob = m0 >> 11, t0 = m0 & 2047;
    #pragma unroll
    for (int nt = 0; nt < 3; nt++) {
        int nl = w * 48 + nt * 16 + fr;
        #pragma unroll
        for (int mt = 0; mt < 2; mt++)
            #pragma unroll
            for (int r = 0; r < 4; r++) {
                int ml = mt * 16 + quad * 4 + r;
                Ts[ml][nl] = f2bf(acc[mt][nt][r]);
            }
    }
    __syncthreads();
    // coalesced qbf: 32 rows x 3 heads x 8 uint4 = 768 uint4 stores, 3 per thread
    #pragma unroll
    for (int it = 0; it < 3; it++) {
        int idx = it * 256 + tid;
        int row = idx / 24, piece = idx % 24;
        int head = piece >> 3, q = piece & 7;
        int hg = blockIdx.y * 3 + head;
        unsigned short* dst = qbf + ((size_t)(bglob * HH + hg) * TT + t0 + row) * DD + q * 8;
        *(uint4*)dst = *(const uint4*)&Ts[row][head * 64 + q * 8];
    }
    if (tid < 192) {
        int nl = tid;
        int n = blockIdx.y * 192 + nl;
        int h = n >> 6, d = n & 63;
        unsigned short tmp[32];
        #pragma unroll
        for (int i = 0; i < 32; i++) tmp[i] = Ts[i][nl];
        unsigned short* dst = qbfT + ((size_t)(bglob * HH + h) * DD + d) * TT + t0;
        *(uint4*)(dst)      = *(const uint4*)&tmp[0];
        *(uint4*)(dst + 8)  = *(const uint4*)&tmp[8];
        *(uint4*)(dst + 16) = *(const uint4*)&tmp[16];
        *(uint4*)(dst + 24) = *(const uint4*)&tmp[24];
    }
}

// ------------- MFMA flash attention (R29: perfect-balance pairing (2k, 2k+1)) -------
// R24's pairs (p, 63-p) balanced BLOCKS but parked tile-p waves after their diagonal:
// compute-slot utilization 67%, and the block iterated nktB=(63-p)/2+1 times
// (sum 784/head). Pairing (2k, 2k+1) gives both tiles IDENTICAL nkt=k+1: zero
// parking (100% utilization) and 33% fewer staging/barrier iterations (sum 528/head).
// Cross-block imbalance (1..32 iters) handled by longest-first (k descending) +
// 3 blocks/CU backfill. Epilogue/barrier invariants unchanged; numerics unchanged
// (tile 2k's edge keys above the diagonal mask to zero as before).
__global__ __launch_bounds__(512, 6) void k_attn(const unsigned short* __restrict__ qbf,
                                                 const unsigned short* __restrict__ qbfT,
                                                 unsigned short* __restrict__ cat)
{
    __shared__ unsigned short Ks[2][64][72];
    __shared__ unsigned short Vs[2][64][72];
    __shared__ unsigned short Ps[64][76];
    __shared__ float lsc[64];
    float (*Oc)[68] = (float(*)[68])&Ks[0][0][0];   // overlay 64x68x4 = 17408 <= 18432

    const int id = blockIdx.x;              // 0..767
    const int xcd = id & 7, j = id >> 3;
    const int bh = xcd * 3 + (j % 3);       // XCD-affine: 3 heads per XCD
    const int kk = 31 - j / 3;              // 31..0 => longest blocks dispatch first
    const int bb = bh / HH, hh = bh % HH;
    const int tid = threadIdx.x;
    const int w = tid >> 6, lane = tid & 63;
    const int tg = w >> 2, wv = w & 3;      // tile group (0: tile 2k, 1: tile 2k+1)
    const int qhalf = wv & 1, keyhalf = wv >> 1;
    const int fr = lane & 15, quad = lane >> 4;
    const int fc = quad * 8;
    const unsigned short* qb  = qbf  + (size_t)bh * TT * DD;
    const unsigned short* qtb = qbfT + (size_t)bh * DD * TT;
    const int lr = tid >> 3, lc = (tid & 7) * 8;   // 512-thr staging: 1 uint4 K + 1 V
    const float EXSC = 0.18033688011112042f;       // 0.125 * log2(e)

    const int tile = 2 * kk + tg;
    const int m0 = tile * 32;
    const int nkt = kk + 1;                 // IDENTICAL for both tile groups

    // ---- prologue: stage K/V tile 0 + load Q frags (direct, coalesced) ----
    {
        uint4 kr0 = *(const uint4*)(qb + (size_t)lr * DD + lc);
        uint4 vr0 = *(const uint4*)(qtb + (size_t)lr * TT + lc);
        *(uint4*)&Ks[0][lr][lc] = kr0;
        *(uint4*)&Vs[0][lr][lc] = vr0;
    }
    const unsigned short* qp = qb + (size_t)(m0 + qhalf * 16 + fr) * DD + fc;
    const bf16x8 qA0 = *(const bf16x8*)(qp);
    const bf16x8 qA1 = *(const bf16x8*)(qp + 32);
    __syncthreads();   // buf0 visible

    f32x4 accO[4];
    #pragma unroll
    for (int dt = 0; dt < 4; dt++) accO[dt] = (f32x4){0.f, 0.f, 0.f, 0.f};
    float ls[4] = {0.f, 0.f, 0.f, 0.f};
    const int rowbase = m0 + qhalf * 16 + quad * 4;
    const int prow = tg * 32 + qhalf * 16 + quad * 4;   // row in shared Ps/Oc/lsc space

    uint4 kr, vr;
    for (int kt = 0; kt < nkt; kt++) {
        const int cur = kt & 1;
        const int s0 = kt * 64;
        if (kt < nkt - 1) {   // prefetch next K/V tile into regs (full-iter cover)
            kr = *(const uint4*)(qb + (size_t)(s0 + 64 + lr) * DD + lc);
            vr = *(const uint4*)(qtb + (size_t)lr * TT + s0 + 64 + lc);
        }

        {
            f32x4 S[2];
            #pragma unroll
            for (int nt = 0; nt < 2; nt++) {
                f32x4 acc = (f32x4){0.f, 0.f, 0.f, 0.f};
                bf16x8 b0 = *(const bf16x8*)&Ks[cur][keyhalf * 32 + nt * 16 + fr][fc];
                acc = __builtin_amdgcn_mfma_f32_16x16x32_bf16(qA0, b0, acc, 0, 0, 0);
                bf16x8 b1 = *(const bf16x8*)&Ks[cur][keyhalf * 32 + nt * 16 + fr][fc + 32];
                acc = __builtin_amdgcn_mfma_f32_16x16x32_bf16(qA1, b1, acc, 0, 0, 0);
                S[nt] = acc;
            }

            const bool edge = (kt == nkt - 1);
            #pragma unroll
            for (int nt = 0; nt < 2; nt++) {
                const int col = keyhalf * 32 + nt * 16 + fr;
                float pv[4];
                if (edge) {
                    const int jg = s0 + col;
                    #pragma unroll
                    for (int r = 0; r < 4; r++) {
                        float s = S[nt][r];
                        pv[r] = (jg <= rowbase + r && s != 0.0f)
                                ? __builtin_amdgcn_exp2f(s * EXSC) : 0.0f;
                        ls[r] += pv[r];
                    }
                } else {       // fully below diagonal: no causal compare needed
                    #pragma unroll
                    for (int r = 0; r < 4; r++) {
                        float s = S[nt][r];
                        pv[r] = (s != 0.0f) ? __builtin_amdgcn_exp2f(s * EXSC) : 0.0f;
                        ls[r] += pv[r];
                    }
                }
                unsigned int pk0 = cvtpk(pv[0], pv[1]);
                unsigned int pk1 = cvtpk(pv[2], pv[3]);
                Ps[prow + 0][col] = (unsigned short)(pk0);
                Ps[prow + 1][col] = (unsigned short)(pk0 >> 16);
                Ps[prow + 2][col] = (unsigned short)(pk1);
                Ps[prow + 3][col] = (unsigned short)(pk1 >> 16);
            }

            // P exchange is intra-wave (own tg/qhalf/keyhalf quadrant): no barrier
            bf16x8 pA = *(const bf16x8*)&Ps[tg * 32 + qhalf * 16 + fr][keyhalf * 32 + fc];
            #pragma unroll
            for (int dt = 0; dt < 4; dt++) {
                bf16x8 v0 = *(const bf16x8*)&Vs[cur][dt * 16 + fr][keyhalf * 32 + fc];
                accO[dt] = __builtin_amdgcn_mfma_f32_16x16x32_bf16(pA, v0, accO[dt], 0, 0, 0);
            }
        }

        if (kt < nkt - 1) {
            *(uint4*)&Ks[cur ^ 1][lr][lc] = kr;
            *(uint4*)&Vs[cur ^ 1][lr][lc] = vr;
            __syncthreads();   // single barrier per iteration (R20 invariant)
        }
    }

    __syncthreads();   // final-iter LDS reads complete before Oc-overlay write
    #pragma unroll
    for (int r = 0; r < 4; r++) {
        #pragma unroll
        for (int o = 1; o < 16; o <<= 1) ls[r] += __shfl_xor(ls[r], o, 64);
    }
    if (keyhalf == 1) {
        #pragma unroll
        for (int dt = 0; dt < 4; dt++)
            #pragma unroll
            for (int r = 0; r < 4; r++)
                Oc[prow + r][dt * 16 + fr] = accO[dt][r];
        if (fr == 0) {
            #pragma unroll
            for (int r = 0; r < 4; r++) lsc[prow + r] = ls[r];
        }
    }
    __syncthreads();
    if (keyhalf == 0) {
        float il[4];
        #pragma unroll
        for (int r = 0; r < 4; r++) il[r] = 1.0f / (ls[r] + lsc[prow + r]);
        #pragma unroll
        for (int dt = 0; dt < 4; dt++) {
            #pragma unroll
            for (int r = 0; r < 4; r++) {
                float o = accO[dt][r] + Oc[prow + r][dt * 16 + fr];
                int t = rowbase + r;
                cat[((size_t)bb * TT + t) * EE + hh * DD + dt * 16 + fr] =
                    f2bf(o * il[r]);
            }
        }
    }
}

// ------------- fused proj+LN1 + FFN1 + FFN2+LN2 (R27, unchanged) --------------------
// GEMM1's A staged once cooperatively into H1s (dead until GEMM2 epilogue); x/bo
// hoisted to registers at kernel start (drain at the staging barrier).
__global__ __launch_bounds__(512, 2) void k_ffn(const unsigned short* __restrict__ catb,
                                                const unsigned short* __restrict__ wob,
                                                const float* __restrict__ bo,
                                                const float* __restrict__ x,
                                                const float* __restrict__ g1,
                                                const float* __restrict__ be1,
                                                const unsigned short* __restrict__ w1b,
                                                const float* __restrict__ b1,
                                                const unsigned short* __restrict__ w2b,
                                                const float* __restrict__ b2,
                                                const float* __restrict__ g2,
                                                const float* __restrict__ be2,
                                                float* __restrict__ out)
{
    __shared__ unsigned short X1s[32][392];
    __shared__ unsigned short H1s[32][392];
    __shared__ float ssum[32][8];
    __shared__ float ssq[32][8];
    const int tid = threadIdx.x;
    const int w = tid >> 6, lane = tid & 63;
    const int fr = lane & 15, quad = lane >> 4;
    const int m0 = blockIdx.x * 32;
    const int n0 = w * 48;

    f32x4 acc[2][3];
    bf16x8 bC[3], bN[3], bT[3];
    const unsigned short* Wp1 = w1b + (size_t)(n0 + fr) * EE + quad * 8;
    const unsigned short* Wp2 = w2b + (size_t)(n0 + fr) * EE + quad * 8;

    // ---- stage catb A-tile -> H1s (cooperative, coalesced, once per block) ----
    {
        const unsigned short* cp = catb + (size_t)m0 * EE;
        #pragma unroll
        for (int c = 0; c < 3; c++) {
            int idx = c * 4096 + tid * 8;
            int row = idx / EE, col = idx % EE;
            *(uint4*)&H1s[row][col] = *(const uint4*)(cp + idx);
        }
    }
    // ---- hoist x residual + bo to registers (drain at staging barrier) ----
    float xr[2][3][4];
    float bor[3];
    #pragma unroll
    for (int nt = 0; nt < 3; nt++) {
        int n = n0 + nt * 16 + fr;
        bor[nt] = bo[n];
        #pragma unroll
        for (int mt = 0; mt < 2; mt++)
            #pragma unroll
            for (int r = 0; r < 4; r++)
                xr[mt][nt][r] = x[(size_t)(m0 + mt * 16 + quad * 4 + r) * EE + n];
    }

    // ================= GEMM1: proj = catb @ Wo^T (A from LDS) =================
    {
        const unsigned short* Wp = wob + (size_t)(n0 + fr) * EE + quad * 8;
        #pragma unroll
        for (int mt = 0; mt < 2; mt++)
            #pragma unroll
            for (int nt = 0; nt < 3; nt++) acc[mt][nt] = (f32x4){0.f, 0.f, 0.f, 0.f};
        #pragma unroll
        for (int nt = 0; nt < 3; nt++) bC[nt] = *(const bf16x8*)(Wp + (size_t)nt * 16 * EE);
        #pragma unroll
        for (int nt = 0; nt < 3; nt++) bN[nt] = *(const bf16x8*)(Wp + (size_t)nt * 16 * EE + 32);
        #pragma unroll
        for (int nt = 0; nt < 3; nt++) bT[nt] = bN[nt];
        __syncthreads();   // H1s A-tile visible (also drains xr/bor loads)
        #pragma unroll
        for (int k0 = 0; k0 < 12; k0++) {
            if (k0 < 10) {
                #pragma unroll
                for (int nt = 0; nt < 3; nt++)
                    bT[nt] = *(const bf16x8*)(Wp + (size_t)nt * 16 * EE + (k0 + 2) * 32);
            }
            bf16x8 a0 = *(const bf16x8*)&H1s[fr][k0 * 32 + quad * 8];
            bf16x8 a1 = *(const bf16x8*)&H1s[16 + fr][k0 * 32 + quad * 8];
            #pragma unroll
            for (int nt = 0; nt < 3; nt++) {
                acc[0][nt] = __builtin_amdgcn_mfma_f32_16x16x32_bf16(a0, bC[nt], acc[0][nt], 0, 0, 0);
                acc[1][nt] = __builtin_amdgcn_mfma_f32_16x16x32_bf16(a1, bC[nt], acc[1][nt], 0, 0, 0);
            }
            #pragma unroll
            for (int nt = 0; nt < 3; nt++) { bC[nt] = bN[nt]; bN[nt] = bT[nt]; }
        }
    }
    // early prefetch of GEMM2's first two weight stages (overlaps LN1 VALU)
    #pragma unroll
    for (int nt = 0; nt < 3; nt++) bC[nt] = *(const bf16x8*)(Wp1 + (size_t)nt * 16 * EE);
    #pragma unroll
    for (int nt = 0; nt < 3; nt++) bN[nt] = *(const bf16x8*)(Wp1 + (size_t)nt * 16 * EE + 32);
    // + bo + resid(x) -> LN1 stats (x/bo already in registers)
    {
        float s1[2][4] = {{0.f,0.f,0.f,0.f},{0.f,0.f,0.f,0.f}};
        float s2[2][4] = {{0.f,0.f,0.f,0.f},{0.f,0.f,0.f,0.f}};
        #pragma unroll
        for (int nt = 0; nt < 3; nt++) {
            #pragma unroll
            for (int mt = 0; mt < 2; mt++)
                #pragma unroll
                for (int r = 0; r < 4; r++) {
                    float v = acc[mt][nt][r] + bor[nt] + xr[mt][nt][r];
                    acc[mt][nt][r] = v;
                    s1[mt][r] += v;
                    s2[mt][r] += v * v;
                }
        }
        #pragma unroll
        for (int mt = 0; mt < 2; mt++)
            #pragma unroll
            for (int r = 0; r < 4; r++) {
                #pragma unroll
                for (int o = 1; o < 16; o <<= 1) {
                    s1[mt][r] += __shfl_xor(s1[mt][r], o, 64);
                    s2[mt][r] += __shfl_xor(s2[mt][r], o, 64);
                }
            }
        if (fr == 0) {
            #pragma unroll
            for (int mt = 0; mt < 2; mt++)
                #pragma unroll
                for (int r = 0; r < 4; r++) {
                    ssum[mt * 16 + quad * 4 + r][w] = s1[mt][r];
                    ssq [mt * 16 + quad * 4 + r][w] = s2[mt][r];
                }
        }
    }
    __syncthreads();
    {
        #pragma unroll
        for (int mt = 0; mt < 2; mt++) {
            float mu[4], rs[4];
            #pragma unroll
            for (int r = 0; r < 4; r++) {
                int row = mt * 16 + quad * 4 + r;
                float t1 = 0.f, t2 = 0.f;
                #pragma unroll
                for (int q = 0; q < 8; q++) { t1 += ssum[row][q]; t2 += ssq[row][q]; }
                mu[r] = t1 * (1.0f / EE);
                float var = t2 * (1.0f / EE) - mu[r] * mu[r];
                rs[r] = rsqrtf(var + 1e-5f);
            }
            #pragma unroll
            for (int nt = 0; nt < 3; nt++) {
                int n = n0 + nt * 16 + fr;
                float gv = g1[n], bev = be1[n];
                #pragma unroll
                for (int r = 0; r < 4; r++) {
                    float v = (acc[mt][nt][r] - mu[r]) * rs[r] * gv + bev;
                    X1s[mt * 16 + quad * 4 + r][n] = f2bf(v);
                }
            }
        }
    }
    __syncthreads();

    // ================= GEMM2: h1 = relu(x1 @ W1^T + b1) =================
    {
        #pragma unroll
        for (int mt = 0; mt < 2; mt++)
            #pragma unroll
            for (int nt = 0; nt < 3; nt++) acc[mt][nt] = (f32x4){0.f, 0.f, 0.f, 0.f};
        #pragma unroll
        for (int nt = 0; nt < 3; nt++) bT[nt] = bN[nt];
        #pragma unroll
        for (int k0 = 0; k0 < 12; k0++) {
            if (k0 < 10) {
                #pragma unroll
                for (int nt = 0; nt < 3; nt++)
                    bT[nt] = *(const bf16x8*)(Wp1 + (size_t)nt * 16 * EE + (k0 + 2) * 32);
            }
            bf16x8 a0 = *(const bf16x8*)&X1s[fr][k0 * 32 + quad * 8];
            bf16x8 a1 = *(const bf16x8*)&X1s[16 + fr][k0 * 32 + quad * 8];
            #pragma unroll
            for (int nt = 0; nt < 3; nt++) {
                acc[0][nt] = __builtin_amdgcn_mfma_f32_16x16x32_bf16(a0, bC[nt], acc[0][nt], 0, 0, 0);
                acc[1][nt] = __builtin_amdgcn_mfma_f32_16x16x32_bf16(a1, bC[nt], acc[1][nt], 0, 0, 0);
            }
            #pragma unroll
            for (int nt = 0; nt < 3; nt++) { bC[nt] = bN[nt]; bN[nt] = bT[nt]; }
        }
        // early prefetch of GEMM3's first two weight stages (overlaps relu/store VALU)
        #pragma unroll
        for (int nt = 0; nt < 3; nt++) bC[nt] = *(const bf16x8*)(Wp2 + (size_t)nt * 16 * EE);
        #pragma unroll
        for (int nt = 0; nt < 3; nt++) bN[nt] = *(const bf16x8*)(Wp2 + (size_t)nt * 16 * EE + 32);
        __syncthreads();   // GEMM1's H1s A-reads complete before overwrite below
        #pragma unroll
        for (int nt = 0; nt < 3; nt++) {
            int n = n0 + nt * 16 + fr;
            float bv = b1[n];
            #pragma unroll
            for (int mt = 0; mt < 2; mt++)
                #pragma unroll
                for (int r = 0; r < 4; r++)
                    H1s[mt * 16 + quad * 4 + r][n] = f2bf(fmaxf(acc[mt][nt][r] + bv, 0.0f));
        }
    }
    __syncthreads();

    // ================= GEMM3: ff = h1 @ W2^T + b2; LN2(x1 + ff) -> out =================
    {
        #pragma unroll
        for (int mt = 0; mt < 2; mt++)
            #pragma unroll
            for (int nt = 0; nt < 3; nt++) acc[mt][nt] = (f32x4){0.f, 0.f, 0.f, 0.f};
        #pragma unroll
        for (int nt = 0; nt < 3; nt++) bT[nt] = bN[nt];
        #pragma unroll
        for (int k0 = 0; k0 < 12; k0++) {
            if (k0 < 10) {
                #pragma unroll
                for (int nt = 0; nt < 3; nt++)
                    bT[nt] = *(const bf16x8*)(Wp2 + (size_t)nt * 16 * EE + (k0 + 2) * 32);
            }
            bf16x8 a0 = *(const bf16x8*)&H1s[fr][k0 * 32 + quad * 8];
            bf16x8 a1 = *(const bf16x8*)&H1s[16 + fr][k0 * 32 + quad * 8];
            #pragma unroll
            for (int nt = 0; nt < 3; nt++) {
                acc[0][nt] = __builtin_amdgcn_mfma_f32_16x16x32_bf16(a0, bC[nt], acc[0][nt], 0, 0, 0);
                acc[1][nt] = __builtin_amdgcn_mfma_f32_16x16x32_bf16(a1, bC[nt], acc[1][nt], 0, 0, 0);
            }
            #pragma unroll
            for (int nt = 0; nt < 3; nt++) { bC[nt] = bN[nt]; bN[nt] = bT[nt]; }
        }
    }
    {
        float s1[2][4] = {{0.f,0.f,0.f,0.f},{0.f,0.f,0.f,0.f}};
        float s2[2][4] = {{0.f,0.f,0.f,0.f},{0.f,0.f,0.f,0.f}};
        #pragma unroll
        for (int nt = 0; nt < 3; nt++) {
            int n = n0 + nt * 16 + fr;
            float bv = b2[n];
            #pragma unroll
            for (int mt = 0; mt < 2; mt++)
                #pragma unroll
                for (int r = 0; r < 4; r++) {
                    float v = acc[mt][nt][r] + bv + bf2f(X1s[mt * 16 + quad * 4 + r][n]);
                    acc[mt][nt][r] = v;
                    s1[mt][r] += v;
                    s2[mt][r] += v * v;
                }
        }
        #pragma unroll
        for (int mt = 0; mt < 2; mt++)
            #pragma unroll
            for (int r = 0; r < 4; r++) {
                #pragma unroll
                for (int o = 1; o < 16; o <<= 1) {
                    s1[mt][r] += __shfl_xor(s1[mt][r], o, 64);
                    s2[mt][r] += __shfl_xor(s2[mt][r], o, 64);
                }
            }
        if (fr == 0) {
            #pragma unroll
            for (int mt = 0; mt < 2; mt++)
                #pragma unroll
                for (int r = 0; r < 4; r++) {
                    ssum[mt * 16 + quad * 4 + r][w] = s1[mt][r];
                    ssq [mt * 16 + quad * 4 + r][w] = s2[mt][r];
                }
        }
    }
    __syncthreads();
    {
        #pragma unroll
        for (int mt = 0; mt < 2; mt++) {
            float mu[4], rs[4];
            #pragma unroll
            for (int r = 0; r < 4; r++) {
                int row = mt * 16 + quad * 4 + r;
                float u1 = 0.f, u2 = 0.f;
                #pragma unroll
                for (int q = 0; q < 8; q++) { u1 += ssum[row][q]; u2 += ssq[row][q]; }
                mu[r] = u1 * (1.0f / EE);
                float var = u2 * (1.0f / EE) - mu[r] * mu[r];
                rs[r] = rsqrtf(var + 1e-5f);
            }
            #pragma unroll
            for (int nt = 0; nt < 3; nt++) {
                int n = n0 + nt * 16 + fr;
                float gv = g2[n], bev = be2[n];
                #pragma unroll
                for (int r = 0; r < 4; r++)
                    out[(size_t)(m0 + mt * 16 + quad * 4 + r) * EE + n] =
                        (acc[mt][nt][r] - mu[r]) * rs[r] * gv + bev;
            }
        }
    }
}

extern "C" void kernel_launch(void* const* d_in, const int* in_sizes, int n_in,
                              void* d_out, int out_size, void* d_ws, size_t ws_size,
                              hipStream_t stream) {
    (void)in_sizes; (void)n_in; (void)out_size; (void)ws_size;
    const float* x   = (const float*)d_in[0];
    const float* Wq  = (const float*)d_in[1];
    const float* Wo  = (const float*)d_in[2];
    const float* bo  = (const float*)d_in[3];
    const float* W1  = (const float*)d_in[4];
    const float* b1  = (const float*)d_in[5];
    const float* W2  = (const float*)d_in[6];
    const float* b2  = (const float*)d_in[7];
    const float* g1  = (const float*)d_in[8];
    const float* be1 = (const float*)d_in[9];
    const float* g2  = (const float*)d_in[10];
    const float* be2 = (const float*)d_in[11];
    float* out = (float*)d_out;

    float* ws = (float*)d_ws;
    const size_t SZ = (size_t)MM * EE;    // 3,145,728 elems / region (12.6 MB fp32)
    float* S1 = ws + SZ;                   // qbf + qbfT (bf16, fills region exactly)
    float* S2 = ws + 2 * SZ;               // catb (bf16)
    float* S3 = ws + 3 * SZ;               // weight bf16 copies

    unsigned short* qbf  = (unsigned short*)S1;
    unsigned short* qbfT = qbf + (size_t)BB * HH * TT * DD;   // AFTER all of qbf!
    unsigned short* catb = (unsigned short*)S2;
    unsigned short* wqb  = (unsigned short*)S3;
    unsigned short* wob  = wqb + (size_t)EE * EE;
    unsigned short* w1b  = wob + (size_t)EE * EE;
    unsigned short* w2b  = w1b + (size_t)EE * EE;

    k_cvt<<<dim3(4 * 144), dim3(256), 0, stream>>>(Wq, Wo, W1, W2, wqb, wob, w1b, w2b);
    k_qgemm<<<dim3(MM / 32, 2), dim3(256), 0, stream>>>(x, wqb, qbf, qbfT);
    k_attn<<<dim3(768), dim3(512), 0, stream>>>(qbf, qbfT, catb);
    k_ffn<<<dim3(MM / 32), dim3(512), 0, stream>>>(catb, wob, bo, x, g1, be1,
                                                   w1b, b1, w2b, b2, g2, be2, out);
}